// Round 13
// baseline (320.892 us; speedup 1.0000x reference)
//
#include <hip/hip_runtime.h>

typedef __bf16 bf16x8 __attribute__((ext_vector_type(8)));
typedef float  f32x4  __attribute__((ext_vector_type(4)));
typedef _Float16 h2v  __attribute__((ext_vector_type(2)));

__device__ __forceinline__ unsigned short f2bf(float f) {
  unsigned u = __builtin_bit_cast(unsigned, f);
  u += 0x7FFFu + ((u >> 16) & 1u);          // round-to-nearest-even
  return (unsigned short)(u >> 16);
}
__device__ __forceinline__ float bf2f(unsigned short b) {
  unsigned u = ((unsigned)b) << 16;
  return __builtin_bit_cast(float, u);
}
__device__ __forceinline__ float bflo(unsigned q) {
  return __builtin_bit_cast(float, q << 16);
}
__device__ __forceinline__ float bfhi(unsigned q) {
  return __builtin_bit_cast(float, q & 0xFFFF0000u);
}
__device__ __forceinline__ unsigned pack2bf(float lo, float hi) {
  return (unsigned)f2bf(lo) | ((unsigned)f2bf(hi) << 16);
}

// ---- fp8 e4m3 bit tricks ----------------------------------------------------
__device__ __forceinline__ float fp8raw(unsigned byte) {   // value * 2^-120
  unsigned b = ((byte & 0x80u) << 24) | ((byte & 0x7Fu) << 20);
  return __builtin_bit_cast(float, b);
}
__device__ __forceinline__ unsigned f2fp8(float v) {       // RNE, |v|<448
  unsigned b = __builtin_bit_cast(unsigned, v);
  unsigned sg = (b >> 24) & 0x80u;
  float a = __builtin_bit_cast(float, b & 0x7FFFFFFFu) * 0x1p-120f;
  unsigned ab = __builtin_bit_cast(unsigned, a);
  ab += 0x7FFFFu + ((ab >> 20) & 1u);
  return sg | ((ab >> 20) & 0x7Fu);
}
// packed decode: word of 4 fp8 bytes -> two f16x2, each f16 = value * 2^-8
__device__ __forceinline__ h2v pkL(unsigned w) {       // (low=e0, high=e2)
  unsigned x = ((w << 8) & 0x80008000u) | ((w << 7) & 0x3F803F80u);
  return __builtin_bit_cast(h2v, x);
}
__device__ __forceinline__ h2v pkH(unsigned w) {       // (low=e1, high=e3)
  unsigned x = (w & 0x80008000u) | ((w >> 1) & 0x3F803F80u);
  return __builtin_bit_cast(h2v, x);
}
__device__ __forceinline__ h2v shfl32(h2v a) {
  return __builtin_bit_cast(h2v,
      __shfl_xor(__builtin_bit_cast(unsigned, a), 32));
}

// ---------------- x -> bf16 + fp8 copies ------------------------------------
__global__ __launch_bounds__(256) void x2bf_kernel(
    const float* __restrict__ x, unsigned short* __restrict__ xh,
    unsigned char* __restrict__ xq, int total8)
{
  const int i = blockIdx.x * 256 + threadIdx.x;
  if (i >= total8) return;
  const float4* p = (const float4*)x + (long)i * 2;
  float4 a = p[0], b = p[1];
  uint4 o;
  o.x = pack2bf(a.x, a.y); o.y = pack2bf(a.z, a.w);
  o.z = pack2bf(b.x, b.y); o.w = pack2bf(b.z, b.w);
  ((uint4*)xh)[i] = o;
  uint2 q;
  q.x = f2fp8(a.x) | (f2fp8(a.y) << 8) | (f2fp8(a.z) << 16) | (f2fp8(a.w) << 24);
  q.y = f2fp8(b.x) | (f2fp8(b.y) << 8) | (f2fp8(b.z) << 16) | (f2fp8(b.w) << 24);
  ((uint2*)xq)[i] = q;
}

// ---------------- prep: W -> Wt (transposed bf16) ----------------------------
__global__ __launch_bounds__(256) void prep_kernel(
    const float* __restrict__ W1, const float* __restrict__ W2,
    unsigned short* __restrict__ Wt1, unsigned short* __restrict__ Wt2)
{
  const int n = blockIdx.x;
  const int k = threadIdx.x;
  Wt1[n * 256 + k] = f2bf(W1[k * 256 + n]);
  Wt2[n * 256 + k] = f2bf(W2[k * 256 + n]);
}

// ------- aggregate: h0 (bf16) + h0q (fp8) = mean over neighbors of xq -------
__global__ __launch_bounds__(256) void aggregate_kernel(
    const unsigned char* __restrict__ xq, const int* __restrict__ nbr,
    unsigned short* __restrict__ h0, unsigned char* __restrict__ h0q, int N)
{
  const int wid  = (blockIdx.x * 256 + threadIdx.x) >> 6;
  const int lane = threadIdx.x & 63;
  if (wid >= N) return;
  const int half = lane >> 5;
  const int l    = lane & 31;
  const int* nb = nbr + (long)wid * 16;
  int4 n0 = ((const int4*)nb)[half * 2];
  int4 n1 = ((const int4*)nb)[half * 2 + 1];
  int v[8] = {n0.x, n0.y, n0.z, n0.w, n1.x, n1.y, n1.z, n1.w};
  int mn = v[0];
#pragma unroll
  for (int t = 1; t < 8; ++t) mn = min(mn, v[t]);

  if (__all(mn >= 0)) {                       // fast path: all 16 valid
    uint2 vals[8];
#pragma unroll
    for (int t = 0; t < 8; ++t)
      vals[t] = ((const uint2*)(xq + (long)v[t] * 256))[l];
    h2v s02 = (h2v)0, s13 = (h2v)0, s46 = (h2v)0, s57 = (h2v)0;
#pragma unroll
    for (int t = 0; t < 8; ++t) {
      s02 = s02 + pkL(vals[t].x);
      s13 = s13 + pkH(vals[t].x);
      s46 = s46 + pkL(vals[t].y);
      s57 = s57 + pkH(vals[t].y);
    }
    s02 = s02 + shfl32(s02);
    s13 = s13 + shfl32(s13);
    s46 = s46 + shfl32(s46);
    s57 = s57 + shfl32(s57);
    if (half == 0) {
      float m[8];                              // mean = sum * 2^8 / 16
      m[0] = (float)s02[0] * 16.f; m[2] = (float)s02[1] * 16.f;
      m[1] = (float)s13[0] * 16.f; m[3] = (float)s13[1] * 16.f;
      m[4] = (float)s46[0] * 16.f; m[6] = (float)s46[1] * 16.f;
      m[5] = (float)s57[0] * 16.f; m[7] = (float)s57[1] * 16.f;
      uint4 o;
      o.x = pack2bf(m[0], m[1]); o.y = pack2bf(m[2], m[3]);
      o.z = pack2bf(m[4], m[5]); o.w = pack2bf(m[6], m[7]);
      ((uint4*)(h0 + (long)wid * 256))[l] = o;
      uint2 q;
      q.x = f2fp8(m[0]) | (f2fp8(m[1]) << 8) | (f2fp8(m[2]) << 16) | (f2fp8(m[3]) << 24);
      q.y = f2fp8(m[4]) | (f2fp8(m[5]) << 8) | (f2fp8(m[6]) << 16) | (f2fp8(m[7]) << 24);
      ((uint2*)(h0q + (long)wid * 256))[l] = q;
    }
    return;
  }
  // slow path: masked mean (scalar decode)
  float wgt[8]; int idx[8];
#pragma unroll
  for (int t = 0; t < 8; ++t) {
    wgt[t] = (v[t] >= 0) ? 1.0f : 0.0f;
    idx[t] = (v[t] >= 0) ? v[t] : 0;
  }
  uint2 vals[8];
#pragma unroll
  for (int t = 0; t < 8; ++t)
    vals[t] = ((const uint2*)(xq + (long)idx[t] * 256))[l];
  float s[8] = {0.f,0.f,0.f,0.f,0.f,0.f,0.f,0.f};
  float cnt = 0.f;
#pragma unroll
  for (int t = 0; t < 8; ++t) {
    const unsigned w0 = vals[t].x, w1 = vals[t].y;
    cnt += wgt[t];
    s[0] = fmaf(wgt[t], fp8raw(w0 & 0xFF), s[0]);
    s[1] = fmaf(wgt[t], fp8raw((w0 >> 8) & 0xFF), s[1]);
    s[2] = fmaf(wgt[t], fp8raw((w0 >> 16) & 0xFF), s[2]);
    s[3] = fmaf(wgt[t], fp8raw(w0 >> 24), s[3]);
    s[4] = fmaf(wgt[t], fp8raw(w1 & 0xFF), s[4]);
    s[5] = fmaf(wgt[t], fp8raw((w1 >> 8) & 0xFF), s[5]);
    s[6] = fmaf(wgt[t], fp8raw((w1 >> 16) & 0xFF), s[6]);
    s[7] = fmaf(wgt[t], fp8raw(w1 >> 24), s[7]);
  }
#pragma unroll
  for (int e = 0; e < 8; ++e) s[e] += __shfl_xor(s[e], 32);
  cnt += __shfl_xor(cnt, 32);
  const float inv = cnt > 0.f ? 0x1p120f / cnt : 0.f;
  if (half == 0) {
    float m[8];
#pragma unroll
    for (int e = 0; e < 8; ++e) m[e] = s[e] * inv;
    uint4 o;
    o.x = pack2bf(m[0], m[1]); o.y = pack2bf(m[2], m[3]);
    o.z = pack2bf(m[4], m[5]); o.w = pack2bf(m[6], m[7]);
    ((uint4*)(h0 + (long)wid * 256))[l] = o;
    uint2 q;
    q.x = f2fp8(m[0]) | (f2fp8(m[1]) << 8) | (f2fp8(m[2]) << 16) | (f2fp8(m[3]) << 24);
    q.y = f2fp8(m[4]) | (f2fp8(m[5]) << 8) | (f2fp8(m[6]) << 16) | (f2fp8(m[7]) << 24);
    ((uint2*)(h0q + (long)wid * 256))[l] = q;
  }
}

// ------- combine: h1 = h0 + alpha*maxpool(h0q, nbrs) + (1+eps)*x ------------
__global__ __launch_bounds__(256) void combine_kernel(
    const unsigned short* __restrict__ h0, const unsigned char* __restrict__ h0q,
    const int* __restrict__ nbr, const unsigned short* __restrict__ xh,
    const float* __restrict__ alpha_p, const float* __restrict__ eps_p,
    unsigned short* __restrict__ h1, int N)
{
  const int wid  = (blockIdx.x * 256 + threadIdx.x) >> 6;
  const int lane = threadIdx.x & 63;
  if (wid >= N) return;
  const int half = lane >> 5;
  const int l    = lane & 31;
  const float alpha = *alpha_p;
  const float c     = 1.0f + *eps_p;
  const int* nb = nbr + (long)wid * 16;
  int4 n0 = ((const int4*)nb)[half * 2];
  int4 n1 = ((const int4*)nb)[half * 2 + 1];
  int v[8] = {n0.x, n0.y, n0.z, n0.w, n1.x, n1.y, n1.z, n1.w};
  int mn = v[0];
#pragma unroll
  for (int t = 1; t < 8; ++t) mn = min(mn, v[t]);

  uint4 own = ((const uint4*)(h0 + (long)wid * 256))[l];
  uint4 xv  = ((const uint4*)(xh + (long)wid * 256))[l];

  if (__all(mn >= 0)) {                       // fast path: packed f16 max
    uint2 vals[8];
#pragma unroll
    for (int t = 0; t < 8; ++t)
      vals[t] = ((const uint2*)(h0q + (long)v[t] * 256))[l];
    const h2v NEG2 = __builtin_bit_cast(h2v, 0xFC00FC00u);   // (-inf,-inf)
    h2v m02 = NEG2, m13 = NEG2, m46 = NEG2, m57 = NEG2;
#pragma unroll
    for (int t = 0; t < 8; ++t) {
      m02 = __builtin_elementwise_max(m02, pkL(vals[t].x));
      m13 = __builtin_elementwise_max(m13, pkH(vals[t].x));
      m46 = __builtin_elementwise_max(m46, pkL(vals[t].y));
      m57 = __builtin_elementwise_max(m57, pkH(vals[t].y));
    }
    m02 = __builtin_elementwise_max(m02, shfl32(m02));
    m13 = __builtin_elementwise_max(m13, shfl32(m13));
    m46 = __builtin_elementwise_max(m46, shfl32(m46));
    m57 = __builtin_elementwise_max(m57, shfl32(m57));
    if (half == 0) {
      float mx[8];                             // true = f16 * 2^8
      mx[0] = (float)m02[0] * 256.f; mx[2] = (float)m02[1] * 256.f;
      mx[1] = (float)m13[0] * 256.f; mx[3] = (float)m13[1] * 256.f;
      mx[4] = (float)m46[0] * 256.f; mx[6] = (float)m46[1] * 256.f;
      mx[5] = (float)m57[0] * 256.f; mx[7] = (float)m57[1] * 256.f;
      const unsigned* qo = (const unsigned*)&own;
      const unsigned* qx = (const unsigned*)&xv;
      uint4 o;
      unsigned* q = (unsigned*)&o;
#pragma unroll
      for (int w = 0; w < 4; ++w) {
        float rl = bflo(qo[w]) + alpha * mx[2*w]   + c * bflo(qx[w]);
        float rh = bfhi(qo[w]) + alpha * mx[2*w+1] + c * bfhi(qx[w]);
        q[w] = pack2bf(rl, rh);
      }
      ((uint4*)(h1 + (long)wid * 256))[l] = o;
    }
    return;
  }
  // slow path: masked max (scalar decode)
  float mx[8];
#pragma unroll
  for (int e = 0; e < 8; ++e) mx[e] = -3.402823466e38f;
  {
    float wgt[8]; int idx[8];
#pragma unroll
    for (int t = 0; t < 8; ++t) {
      wgt[t] = (v[t] >= 0) ? 1.0f : 0.0f;
      idx[t] = (v[t] >= 0) ? v[t] : 0;
    }
    uint2 vals[8];
#pragma unroll
    for (int t = 0; t < 8; ++t)
      vals[t] = ((const uint2*)(h0q + (long)idx[t] * 256))[l];
#pragma unroll
    for (int t = 0; t < 8; ++t) {
      const unsigned w0 = vals[t].x, w1 = vals[t].y;
      const bool valid = wgt[t] > 0.f;
      const float NEG = -3.402823466e38f;
      mx[0] = fmaxf(mx[0], valid ? fp8raw(w0 & 0xFF) * 0x1p120f : NEG);
      mx[1] = fmaxf(mx[1], valid ? fp8raw((w0 >> 8) & 0xFF) * 0x1p120f : NEG);
      mx[2] = fmaxf(mx[2], valid ? fp8raw((w0 >> 16) & 0xFF) * 0x1p120f : NEG);
      mx[3] = fmaxf(mx[3], valid ? fp8raw(w0 >> 24) * 0x1p120f : NEG);
      mx[4] = fmaxf(mx[4], valid ? fp8raw(w1 & 0xFF) * 0x1p120f : NEG);
      mx[5] = fmaxf(mx[5], valid ? fp8raw((w1 >> 8) & 0xFF) * 0x1p120f : NEG);
      mx[6] = fmaxf(mx[6], valid ? fp8raw((w1 >> 16) & 0xFF) * 0x1p120f : NEG);
      mx[7] = fmaxf(mx[7], valid ? fp8raw(w1 >> 24) * 0x1p120f : NEG);
    }
  }
#pragma unroll
  for (int e = 0; e < 8; ++e) mx[e] = fmaxf(mx[e], __shfl_xor(mx[e], 32));
  if (half == 0) {
    const unsigned* qo = (const unsigned*)&own;
    const unsigned* qx = (const unsigned*)&xv;
    uint4 o;
    unsigned* q = (unsigned*)&o;
#pragma unroll
    for (int w = 0; w < 4; ++w) {
      float rl = bflo(qo[w]) + alpha * mx[2*w]   + c * bflo(qx[w]);
      float rh = bfhi(qo[w]) + alpha * mx[2*w+1] + c * bfhi(qx[w]);
      q[w] = pack2bf(rl, rh);
    }
    ((uint4*)(h1 + (long)wid * 256))[l] = o;
  }
}

// ---------------- half-W-stationary GEMM: Out = relu(A @ W + b) -------------
// 256-row x 128-col tile/block; half of Wt (64 KB) in LDS -> 2 blocks/CU.
// 8 waves = 4 row-groups x 2 col-groups; wave = 64x64, acc[4][4]; per kk:
// 4 global af + 4 LDS bq + 16 MFMA. NEW: af register ping-pong prefetch —
// kk+1's global loads issued before kk's MFMA block to hide L3 latency.
template<int WITH_STATS>
__global__ __launch_bounds__(512, 4) void gemm_w_kernel(
    const unsigned short* __restrict__ A, const unsigned short* __restrict__ Wt,
    const float* __restrict__ bias, unsigned short* __restrict__ Out,
    float* __restrict__ partials, int M)
{
  __shared__ __align__(16) unsigned short lW[128 * 256];   // 64 KB
  const int tid  = threadIdx.x;
  const int lane = tid & 63;
  const int wave = tid >> 6;          // 0..7
  const int wm   = wave >> 1;         // row group (64 rows each)
  const int wn   = wave & 1;          // col group (64 cols each)
  const int g = lane >> 4, lr = lane & 15;
  const int colhalf = blockIdx.x & 1;
  const long row0   = (long)(blockIdx.x >> 1) * 256;
  char* lWc = (char*)lW;

  // ---- one-time half-W load, XOR-swizzled rows (512 thr x 128 B) ----
  {
    const int row   = tid >> 2;            // 0..127 (local Wt row = out col)
    const int cbase = (tid & 3) * 128;
    const char* src = (const char*)Wt + (long)(colhalf * 128 + row) * 512 + cbase;
#pragma unroll
    for (int i = 0; i < 8; ++i) {
      uint4 v = *(const uint4*)(src + i * 16);
      *(uint4*)(lWc + ((row * 512 + cbase + i * 16) ^ ((row & 7) << 4))) = v;
    }
  }
  __syncthreads();

  float bv[4];
#pragma unroll
  for (int nt = 0; nt < 4; ++nt)
    bv[nt] = bias[colhalf * 128 + wn * 64 + nt * 16 + lr];

  float s[4] = {0.f, 0.f, 0.f, 0.f}, s2[4] = {0.f, 0.f, 0.f, 0.f};
  const char* Ab = (const char*)A;

  f32x4 acc[4][4] = {};
  const long abase = (row0 + wm * 64 + lr) * 512 + g * 16;

  bf16x8 afc[4], afn[4];
#pragma unroll
  for (int mt = 0; mt < 4; ++mt)
    afc[mt] = *(const bf16x8*)(Ab + abase + mt * (16 * 512));

#pragma unroll
  for (int kk = 0; kk < 8; ++kk) {
    if (kk < 7) {
#pragma unroll
      for (int mt = 0; mt < 4; ++mt)
        afn[mt] = *(const bf16x8*)(Ab + abase + mt * (16 * 512) + (kk + 1) * 64);
    }
    bf16x8 bq[4];
#pragma unroll
    for (int nt = 0; nt < 4; ++nt) {
      const int wrow = wn * 64 + nt * 16 + lr;            // local col 0..127
      bq[nt] = *(const bf16x8*)(lWc +
                 ((wrow * 512 + kk * 64 + g * 16) ^ ((wrow & 7) << 4)));
    }
#pragma unroll
    for (int mt = 0; mt < 4; ++mt)
#pragma unroll
      for (int nt = 0; nt < 4; ++nt)
        acc[mt][nt] = __builtin_amdgcn_mfma_f32_16x16x32_bf16(
            afc[mt], bq[nt], acc[mt][nt], 0, 0, 0);
    if (kk < 7) {
#pragma unroll
      for (int mt = 0; mt < 4; ++mt) afc[mt] = afn[mt];
    }
  }

  // ---- epilogue: bias + relu + store (+ register stats) ----
#pragma unroll
  for (int nt = 0; nt < 4; ++nt) {
    const int col = colhalf * 128 + wn * 64 + nt * 16 + lr;
#pragma unroll
    for (int mt = 0; mt < 4; ++mt) {
      f32x4 vv = acc[mt][nt];
      const long rbase = row0 + wm * 64 + mt * 16 + g * 4;
#pragma unroll
      for (int e = 0; e < 4; ++e) {
        const float val = fmaxf(vv[e] + bv[nt], 0.f);
        Out[(rbase + e) * 256 + col] = f2bf(val);
        if (WITH_STATS) {
          if (rbase + e < M) { s[nt] += val; s2[nt] += val * val; }
        }
      }
    }
  }

  if (WITH_STATS) {
#pragma unroll
    for (int nt = 0; nt < 4; ++nt) {
      s[nt]  += __shfl_xor(s[nt], 16);   s2[nt] += __shfl_xor(s2[nt], 16);
      s[nt]  += __shfl_xor(s[nt], 32);   s2[nt] += __shfl_xor(s2[nt], 32);
    }
    if (g == 0) {
      float* p = partials + ((long)blockIdx.x * 4 + wm) * 256;
#pragma unroll
      for (int nt = 0; nt < 4; ++nt) {
        const int cl = wn * 64 + nt * 16 + lr;            // local col 0..127
        p[cl]       = s[nt];
        p[128 + cl] = s2[nt];
      }
    }
  }
}

// ---------------- BN finalize: parallel reduce (one block per column) -------
__global__ __launch_bounds__(256) void bn_finalize_kernel(
    const float* __restrict__ gamma, const float* __restrict__ beta,
    const float* __restrict__ partials, float* __restrict__ stats,
    int M, int ntiles)
{
  __shared__ float red[8];
  const int n  = blockIdx.x;           // column 0..255
  const int t  = threadIdx.x;
  const int ch = n >> 7;
  const int cl = n & 127;
  const int total = ntiles * 4;        // (tile, wm) pairs
  float s = 0.f, s2 = 0.f;
  for (int j = t; j < total; j += 256) {
    const int k  = j >> 2;
    const int wm = j & 3;
    const float* p = partials + ((long)(2 * k + ch) * 4 + wm) * 256;
    s  += p[cl];
    s2 += p[128 + cl];
  }
#pragma unroll
  for (int off = 32; off >= 1; off >>= 1) {
    s  += __shfl_xor(s, off);
    s2 += __shfl_xor(s2, off);
  }
  if ((t & 63) == 0) { red[(t >> 6) * 2] = s; red[(t >> 6) * 2 + 1] = s2; }
  __syncthreads();
  if (t == 0) {
    s  = red[0] + red[2] + red[4] + red[6];
    s2 = red[1] + red[3] + red[5] + red[7];
    const float invM = 1.0f / (float)M;
    const float mean = s * invM;
    float var = s2 * invM - mean * mean;
    var = fmaxf(var, 0.f);
    const float sc = gamma[n] * rsqrtf(var + 1e-5f);
    stats[512 + n] = sc;
    stats[768 + n] = beta[n] - mean * sc;
  }
}

// ---------------- BN normalize: out = h3*scale + shift (8 elems/thread) -----
__global__ __launch_bounds__(256) void bn_norm_kernel(
    const unsigned short* __restrict__ h3, const float* __restrict__ stats,
    float* __restrict__ out, int total8)
{
  const int i = blockIdx.x * 256 + threadIdx.x;
  if (i >= total8) return;
  uint4 v = ((const uint4*)h3)[i];
  const int c = (i * 8) & 255;
  const float4 sc0 = *(const float4*)&stats[512 + c];
  const float4 sc1 = *(const float4*)&stats[516 + c];
  const float4 sh0 = *(const float4*)&stats[768 + c];
  const float4 sh1 = *(const float4*)&stats[772 + c];
  const unsigned short* u = (const unsigned short*)&v;
  float4 o0, o1;
  o0.x = bf2f(u[0]) * sc0.x + sh0.x;
  o0.y = bf2f(u[1]) * sc0.y + sh0.y;
  o0.z = bf2f(u[2]) * sc0.z + sh0.z;
  o0.w = bf2f(u[3]) * sc0.w + sh0.w;
  o1.x = bf2f(u[4]) * sc1.x + sh1.x;
  o1.y = bf2f(u[5]) * sc1.y + sh1.y;
  o1.z = bf2f(u[6]) * sc1.z + sh1.z;
  o1.w = bf2f(u[7]) * sc1.w + sh1.w;
  ((float4*)out)[2 * i]     = o0;
  ((float4*)out)[2 * i + 1] = o1;
}

// ----------------------------------------------------------------------------
extern "C" void kernel_launch(void* const* d_in, const int* in_sizes, int n_in,
                              void* d_out, int out_size, void* d_ws, size_t ws_size,
                              hipStream_t stream) {
  const float* x     = (const float*)d_in[0];
  const int*   nbr   = (const int*)d_in[1];
  const float* W1    = (const float*)d_in[2];
  const float* b1    = (const float*)d_in[3];
  const float* W2    = (const float*)d_in[4];
  const float* b2    = (const float*)d_in[5];
  const float* gamma = (const float*)d_in[6];
  const float* beta  = (const float*)d_in[7];
  const float* alpha_p = (const float*)d_in[8];
  const float* eps_p   = (const float*)d_in[9];
  float* out = (float*)d_out;

  const int  N  = in_sizes[0] / 256;            // 100000
  const long MP = ((long)N + 255) & ~255L;      // padded rows (100096 = 391*256)
  const int  ntiles = (int)(MP / 256);          // 391

  // ws layout: xh (bf16 x -> h2) | bufA (h0 -> h3) | bufB (xq fp8 -> h1) |
  //            Wt1 | Wt2 | h0q (fp8) | partials (2*ntiles*4 rows x 256) | stats
  unsigned short* xh   = (unsigned short*)d_ws;
  unsigned short* bufA = xh + MP * 256;
  unsigned short* bufB = bufA + MP * 256;
  unsigned short* Wt1  = bufB + MP * 256;
  unsigned short* Wt2  = Wt1 + 256 * 256;
  unsigned char*  h0q  = (unsigned char*)(Wt2 + 256 * 256);   // MP*256 bytes
  float* partials = (float*)(h0q + MP * 256);   // 2*ntiles*4*256 floats
  float* stats    = partials + (long)2 * ntiles * 4 * 256;
  unsigned char*  xq = (unsigned char*)bufB;    // aliases bufB (dead before h1)

  x2bf_kernel<<<(N * 32 + 255) / 256, 256, 0, stream>>>(x, xh, xq, N * 32);
  prep_kernel<<<256, 256, 0, stream>>>(W1, W2, Wt1, Wt2);
  aggregate_kernel<<<(N + 3) / 4, 256, 0, stream>>>(xq, nbr, bufA, h0q, N);
  combine_kernel<<<(N + 3) / 4, 256, 0, stream>>>(bufA, h0q, nbr, xh,
                                                  alpha_p, eps_p, bufB, N);

  gemm_w_kernel<0><<<2 * ntiles, 512, 0, stream>>>(bufB, Wt1, b1, xh, nullptr, N);
  gemm_w_kernel<1><<<2 * ntiles, 512, 0, stream>>>(xh, Wt2, b2, bufA, partials, N);

  bn_finalize_kernel<<<256, 256, 0, stream>>>(gamma, beta, partials, stats, N, ntiles);
  bn_norm_kernel<<<(N * 32 + 255) / 256, 256, 0, stream>>>(bufA, stats, out, N * 32);
}

// Round 14
// 312.054 us; speedup vs baseline: 1.0283x; 1.0283x over previous
//
#include <hip/hip_runtime.h>

typedef __bf16 bf16x8 __attribute__((ext_vector_type(8)));
typedef float  f32x4  __attribute__((ext_vector_type(4)));
typedef _Float16 h2v  __attribute__((ext_vector_type(2)));

__device__ __forceinline__ unsigned short f2bf(float f) {
  unsigned u = __builtin_bit_cast(unsigned, f);
  u += 0x7FFFu + ((u >> 16) & 1u);          // round-to-nearest-even
  return (unsigned short)(u >> 16);
}
__device__ __forceinline__ float bf2f(unsigned short b) {
  unsigned u = ((unsigned)b) << 16;
  return __builtin_bit_cast(float, u);
}
__device__ __forceinline__ float bflo(unsigned q) {
  return __builtin_bit_cast(float, q << 16);
}
__device__ __forceinline__ float bfhi(unsigned q) {
  return __builtin_bit_cast(float, q & 0xFFFF0000u);
}
__device__ __forceinline__ unsigned pack2bf(float lo, float hi) {
  return (unsigned)f2bf(lo) | ((unsigned)f2bf(hi) << 16);
}

// ---- fp8 e4m3 bit tricks ----------------------------------------------------
__device__ __forceinline__ float fp8raw(unsigned byte) {   // value * 2^-120
  unsigned b = ((byte & 0x80u) << 24) | ((byte & 0x7Fu) << 20);
  return __builtin_bit_cast(float, b);
}
__device__ __forceinline__ unsigned f2fp8(float v) {       // RNE, |v|<448
  unsigned b = __builtin_bit_cast(unsigned, v);
  unsigned sg = (b >> 24) & 0x80u;
  float a = __builtin_bit_cast(float, b & 0x7FFFFFFFu) * 0x1p-120f;
  unsigned ab = __builtin_bit_cast(unsigned, a);
  ab += 0x7FFFFu + ((ab >> 20) & 1u);
  return sg | ((ab >> 20) & 0x7Fu);
}
// packed decode: word of 4 fp8 bytes -> two f16x2, each f16 = value * 2^-8
__device__ __forceinline__ h2v pkL(unsigned w) {       // (low=e0, high=e2)
  unsigned x = ((w << 8) & 0x80008000u) | ((w << 7) & 0x3F803F80u);
  return __builtin_bit_cast(h2v, x);
}
__device__ __forceinline__ h2v pkH(unsigned w) {       // (low=e1, high=e3)
  unsigned x = (w & 0x80008000u) | ((w >> 1) & 0x3F803F80u);
  return __builtin_bit_cast(h2v, x);
}
__device__ __forceinline__ h2v shfl32(h2v a) {
  return __builtin_bit_cast(h2v,
      __shfl_xor(__builtin_bit_cast(unsigned, a), 32));
}

// ---------------- x -> bf16 + fp8 copies ------------------------------------
__global__ __launch_bounds__(256) void x2bf_kernel(
    const float* __restrict__ x, unsigned short* __restrict__ xh,
    unsigned char* __restrict__ xq, int total8)
{
  const int i = blockIdx.x * 256 + threadIdx.x;
  if (i >= total8) return;
  const float4* p = (const float4*)x + (long)i * 2;
  float4 a = p[0], b = p[1];
  uint4 o;
  o.x = pack2bf(a.x, a.y); o.y = pack2bf(a.z, a.w);
  o.z = pack2bf(b.x, b.y); o.w = pack2bf(b.z, b.w);
  ((uint4*)xh)[i] = o;
  uint2 q;
  q.x = f2fp8(a.x) | (f2fp8(a.y) << 8) | (f2fp8(a.z) << 16) | (f2fp8(a.w) << 24);
  q.y = f2fp8(b.x) | (f2fp8(b.y) << 8) | (f2fp8(b.z) << 16) | (f2fp8(b.w) << 24);
  ((uint2*)xq)[i] = q;
}

// ---------------- prep: W -> Wt (transposed bf16) ----------------------------
__global__ __launch_bounds__(256) void prep_kernel(
    const float* __restrict__ W1, const float* __restrict__ W2,
    unsigned short* __restrict__ Wt1, unsigned short* __restrict__ Wt2)
{
  const int n = blockIdx.x;
  const int k = threadIdx.x;
  Wt1[n * 256 + k] = f2bf(W1[k * 256 + n]);
  Wt2[n * 256 + k] = f2bf(W2[k * 256 + n]);
}

// ------- aggregate: h0 (bf16) + h0q (fp8) = mean over neighbors of xq -------
__global__ __launch_bounds__(256) void aggregate_kernel(
    const unsigned char* __restrict__ xq, const int* __restrict__ nbr,
    unsigned short* __restrict__ h0, unsigned char* __restrict__ h0q, int N)
{
  const int wid  = (blockIdx.x * 256 + threadIdx.x) >> 6;
  const int lane = threadIdx.x & 63;
  if (wid >= N) return;
  const int half = lane >> 5;
  const int l    = lane & 31;
  const unsigned lb = (unsigned)(l << 3);       // lane byte offset in row
  const int* nb = nbr + (long)wid * 16;
  int4 n0 = ((const int4*)nb)[half * 2];
  int4 n1 = ((const int4*)nb)[half * 2 + 1];
  int v[8] = {n0.x, n0.y, n0.z, n0.w, n1.x, n1.y, n1.z, n1.w};
  int mn = v[0];
#pragma unroll
  for (int t = 1; t < 8; ++t) mn = min(mn, v[t]);

  if (__all(mn >= 0)) {                       // fast path: all 16 valid
    uint2 vals[8];
#pragma unroll
    for (int t = 0; t < 8; ++t)
      vals[t] = *(const uint2*)(xq + (((unsigned)v[t] << 8) | lb));
    h2v s02 = (h2v)0, s13 = (h2v)0, s46 = (h2v)0, s57 = (h2v)0;
#pragma unroll
    for (int t = 0; t < 8; ++t) {
      s02 = s02 + pkL(vals[t].x);
      s13 = s13 + pkH(vals[t].x);
      s46 = s46 + pkL(vals[t].y);
      s57 = s57 + pkH(vals[t].y);
    }
    s02 = s02 + shfl32(s02);
    s13 = s13 + shfl32(s13);
    s46 = s46 + shfl32(s46);
    s57 = s57 + shfl32(s57);
    if (half == 0) {
      float m[8];                              // mean = sum * 2^8 / 16
      m[0] = (float)s02[0] * 16.f; m[2] = (float)s02[1] * 16.f;
      m[1] = (float)s13[0] * 16.f; m[3] = (float)s13[1] * 16.f;
      m[4] = (float)s46[0] * 16.f; m[6] = (float)s46[1] * 16.f;
      m[5] = (float)s57[0] * 16.f; m[7] = (float)s57[1] * 16.f;
      uint4 o;
      o.x = pack2bf(m[0], m[1]); o.y = pack2bf(m[2], m[3]);
      o.z = pack2bf(m[4], m[5]); o.w = pack2bf(m[6], m[7]);
      *(uint4*)((char*)h0 + (((unsigned)wid << 9) | (lb << 1))) = o;
      uint2 q;
      q.x = f2fp8(m[0]) | (f2fp8(m[1]) << 8) | (f2fp8(m[2]) << 16) | (f2fp8(m[3]) << 24);
      q.y = f2fp8(m[4]) | (f2fp8(m[5]) << 8) | (f2fp8(m[6]) << 16) | (f2fp8(m[7]) << 24);
      *(uint2*)(h0q + (((unsigned)wid << 8) | lb)) = q;
    }
    return;
  }
  // slow path: masked mean (scalar decode)
  float wgt[8]; int idx[8];
#pragma unroll
  for (int t = 0; t < 8; ++t) {
    wgt[t] = (v[t] >= 0) ? 1.0f : 0.0f;
    idx[t] = (v[t] >= 0) ? v[t] : 0;
  }
  uint2 vals[8];
#pragma unroll
  for (int t = 0; t < 8; ++t)
    vals[t] = *(const uint2*)(xq + (((unsigned)idx[t] << 8) | lb));
  float s[8] = {0.f,0.f,0.f,0.f,0.f,0.f,0.f,0.f};
  float cnt = 0.f;
#pragma unroll
  for (int t = 0; t < 8; ++t) {
    const unsigned w0 = vals[t].x, w1 = vals[t].y;
    cnt += wgt[t];
    s[0] = fmaf(wgt[t], fp8raw(w0 & 0xFF), s[0]);
    s[1] = fmaf(wgt[t], fp8raw((w0 >> 8) & 0xFF), s[1]);
    s[2] = fmaf(wgt[t], fp8raw((w0 >> 16) & 0xFF), s[2]);
    s[3] = fmaf(wgt[t], fp8raw(w0 >> 24), s[3]);
    s[4] = fmaf(wgt[t], fp8raw(w1 & 0xFF), s[4]);
    s[5] = fmaf(wgt[t], fp8raw((w1 >> 8) & 0xFF), s[5]);
    s[6] = fmaf(wgt[t], fp8raw((w1 >> 16) & 0xFF), s[6]);
    s[7] = fmaf(wgt[t], fp8raw(w1 >> 24), s[7]);
  }
#pragma unroll
  for (int e = 0; e < 8; ++e) s[e] += __shfl_xor(s[e], 32);
  cnt += __shfl_xor(cnt, 32);
  const float inv = cnt > 0.f ? 0x1p120f / cnt : 0.f;
  if (half == 0) {
    float m[8];
#pragma unroll
    for (int e = 0; e < 8; ++e) m[e] = s[e] * inv;
    uint4 o;
    o.x = pack2bf(m[0], m[1]); o.y = pack2bf(m[2], m[3]);
    o.z = pack2bf(m[4], m[5]); o.w = pack2bf(m[6], m[7]);
    *(uint4*)((char*)h0 + (((unsigned)wid << 9) | (lb << 1))) = o;
    uint2 q;
    q.x = f2fp8(m[0]) | (f2fp8(m[1]) << 8) | (f2fp8(m[2]) << 16) | (f2fp8(m[3]) << 24);
    q.y = f2fp8(m[4]) | (f2fp8(m[5]) << 8) | (f2fp8(m[6]) << 16) | (f2fp8(m[7]) << 24);
    *(uint2*)(h0q + (((unsigned)wid << 8) | lb)) = q;
  }
}

// ------- combine: h1 = h0 + alpha*maxpool(h0q, nbrs) + (1+eps)*x ------------
__global__ __launch_bounds__(256) void combine_kernel(
    const unsigned short* __restrict__ h0, const unsigned char* __restrict__ h0q,
    const int* __restrict__ nbr, const unsigned short* __restrict__ xh,
    const float* __restrict__ alpha_p, const float* __restrict__ eps_p,
    unsigned short* __restrict__ h1, int N)
{
  const int wid  = (blockIdx.x * 256 + threadIdx.x) >> 6;
  const int lane = threadIdx.x & 63;
  if (wid >= N) return;
  const int half = lane >> 5;
  const int l    = lane & 31;
  const unsigned lb = (unsigned)(l << 3);       // lane byte offset (fp8 row)
  const float alpha = *alpha_p;
  const float c     = 1.0f + *eps_p;
  const int* nb = nbr + (long)wid * 16;
  int4 n0 = ((const int4*)nb)[half * 2];
  int4 n1 = ((const int4*)nb)[half * 2 + 1];
  int v[8] = {n0.x, n0.y, n0.z, n0.w, n1.x, n1.y, n1.z, n1.w};
  int mn = v[0];
#pragma unroll
  for (int t = 1; t < 8; ++t) mn = min(mn, v[t]);

  uint4 own = *(const uint4*)((const char*)h0 + (((unsigned)wid << 9) | (lb << 1)));
  uint4 xv  = *(const uint4*)((const char*)xh + (((unsigned)wid << 9) | (lb << 1)));

  if (__all(mn >= 0)) {                       // fast path: packed f16 max
    uint2 vals[8];
#pragma unroll
    for (int t = 0; t < 8; ++t)
      vals[t] = *(const uint2*)(h0q + (((unsigned)v[t] << 8) | lb));
    const h2v NEG2 = __builtin_bit_cast(h2v, 0xFC00FC00u);   // (-inf,-inf)
    h2v m02 = NEG2, m13 = NEG2, m46 = NEG2, m57 = NEG2;
#pragma unroll
    for (int t = 0; t < 8; ++t) {
      m02 = __builtin_elementwise_max(m02, pkL(vals[t].x));
      m13 = __builtin_elementwise_max(m13, pkH(vals[t].x));
      m46 = __builtin_elementwise_max(m46, pkL(vals[t].y));
      m57 = __builtin_elementwise_max(m57, pkH(vals[t].y));
    }
    m02 = __builtin_elementwise_max(m02, shfl32(m02));
    m13 = __builtin_elementwise_max(m13, shfl32(m13));
    m46 = __builtin_elementwise_max(m46, shfl32(m46));
    m57 = __builtin_elementwise_max(m57, shfl32(m57));
    if (half == 0) {
      float mx[8];                             // true = f16 * 2^8
      mx[0] = (float)m02[0] * 256.f; mx[2] = (float)m02[1] * 256.f;
      mx[1] = (float)m13[0] * 256.f; mx[3] = (float)m13[1] * 256.f;
      mx[4] = (float)m46[0] * 256.f; mx[6] = (float)m46[1] * 256.f;
      mx[5] = (float)m57[0] * 256.f; mx[7] = (float)m57[1] * 256.f;
      const unsigned* qo = (const unsigned*)&own;
      const unsigned* qx = (const unsigned*)&xv;
      uint4 o;
      unsigned* q = (unsigned*)&o;
#pragma unroll
      for (int w = 0; w < 4; ++w) {
        float rl = bflo(qo[w]) + alpha * mx[2*w]   + c * bflo(qx[w]);
        float rh = bfhi(qo[w]) + alpha * mx[2*w+1] + c * bfhi(qx[w]);
        q[w] = pack2bf(rl, rh);
      }
      *(uint4*)((char*)h1 + (((unsigned)wid << 9) | (lb << 1))) = o;
    }
    return;
  }
  // slow path: masked max (scalar decode)
  float mx[8];
#pragma unroll
  for (int e = 0; e < 8; ++e) mx[e] = -3.402823466e38f;
  {
    float wgt[8]; int idx[8];
#pragma unroll
    for (int t = 0; t < 8; ++t) {
      wgt[t] = (v[t] >= 0) ? 1.0f : 0.0f;
      idx[t] = (v[t] >= 0) ? v[t] : 0;
    }
    uint2 vals[8];
#pragma unroll
    for (int t = 0; t < 8; ++t)
      vals[t] = *(const uint2*)(h0q + (((unsigned)idx[t] << 8) | lb));
#pragma unroll
    for (int t = 0; t < 8; ++t) {
      const unsigned w0 = vals[t].x, w1 = vals[t].y;
      const bool valid = wgt[t] > 0.f;
      const float NEG = -3.402823466e38f;
      mx[0] = fmaxf(mx[0], valid ? fp8raw(w0 & 0xFF) * 0x1p120f : NEG);
      mx[1] = fmaxf(mx[1], valid ? fp8raw((w0 >> 8) & 0xFF) * 0x1p120f : NEG);
      mx[2] = fmaxf(mx[2], valid ? fp8raw((w0 >> 16) & 0xFF) * 0x1p120f : NEG);
      mx[3] = fmaxf(mx[3], valid ? fp8raw(w0 >> 24) * 0x1p120f : NEG);
      mx[4] = fmaxf(mx[4], valid ? fp8raw(w1 & 0xFF) * 0x1p120f : NEG);
      mx[5] = fmaxf(mx[5], valid ? fp8raw((w1 >> 8) & 0xFF) * 0x1p120f : NEG);
      mx[6] = fmaxf(mx[6], valid ? fp8raw((w1 >> 16) & 0xFF) * 0x1p120f : NEG);
      mx[7] = fmaxf(mx[7], valid ? fp8raw(w1 >> 24) * 0x1p120f : NEG);
    }
  }
#pragma unroll
  for (int e = 0; e < 8; ++e) mx[e] = fmaxf(mx[e], __shfl_xor(mx[e], 32));
  if (half == 0) {
    const unsigned* qo = (const unsigned*)&own;
    const unsigned* qx = (const unsigned*)&xv;
    uint4 o;
    unsigned* q = (unsigned*)&o;
#pragma unroll
    for (int w = 0; w < 4; ++w) {
      float rl = bflo(qo[w]) + alpha * mx[2*w]   + c * bflo(qx[w]);
      float rh = bfhi(qo[w]) + alpha * mx[2*w+1] + c * bfhi(qx[w]);
      q[w] = pack2bf(rl, rh);
    }
    *(uint4*)((char*)h1 + (((unsigned)wid << 9) | (lb << 1))) = o;
  }
}

// ---------------- half-W-stationary GEMM: Out = relu(A @ W + b) -------------
// 256-row x 128-col tile/block; half of Wt (64 KB) in LDS -> 2 blocks/CU.
// 8 waves = 4 row-groups x 2 col-groups; wave = 64x64, acc[4][4]; per kk:
// 4 global af + 4 LDS bq + 16 MFMA (MFMA:global ratio 4).
template<int WITH_STATS>
__global__ __launch_bounds__(512, 4) void gemm_w_kernel(
    const unsigned short* __restrict__ A, const unsigned short* __restrict__ Wt,
    const float* __restrict__ bias, unsigned short* __restrict__ Out,
    float* __restrict__ partials, int M)
{
  __shared__ __align__(16) unsigned short lW[128 * 256];   // 64 KB
  const int tid  = threadIdx.x;
  const int lane = tid & 63;
  const int wave = tid >> 6;          // 0..7
  const int wm   = wave >> 1;         // row group (64 rows each)
  const int wn   = wave & 1;          // col group (64 cols each)
  const int g = lane >> 4, lr = lane & 15;
  const int colhalf = blockIdx.x & 1;
  const long row0   = (long)(blockIdx.x >> 1) * 256;
  char* lWc = (char*)lW;

  // ---- one-time half-W load, XOR-swizzled rows (512 thr x 128 B) ----
  {
    const int row   = tid >> 2;            // 0..127 (local Wt row = out col)
    const int cbase = (tid & 3) * 128;
    const char* src = (const char*)Wt + (long)(colhalf * 128 + row) * 512 + cbase;
#pragma unroll
    for (int i = 0; i < 8; ++i) {
      uint4 v = *(const uint4*)(src + i * 16);
      *(uint4*)(lWc + ((row * 512 + cbase + i * 16) ^ ((row & 7) << 4))) = v;
    }
  }
  __syncthreads();

  float bv[4];
#pragma unroll
  for (int nt = 0; nt < 4; ++nt)
    bv[nt] = bias[colhalf * 128 + wn * 64 + nt * 16 + lr];

  float s[4] = {0.f, 0.f, 0.f, 0.f}, s2[4] = {0.f, 0.f, 0.f, 0.f};
  const char* Ab = (const char*)A;

  f32x4 acc[4][4] = {};
  const long abase = (row0 + wm * 64 + lr) * 512 + g * 16;
#pragma unroll
  for (int kk = 0; kk < 8; ++kk) {
    bf16x8 af[4], bq[4];
#pragma unroll
    for (int mt = 0; mt < 4; ++mt)
      af[mt] = *(const bf16x8*)(Ab + abase + mt * (16 * 512) + kk * 64);
#pragma unroll
    for (int nt = 0; nt < 4; ++nt) {
      const int wrow = wn * 64 + nt * 16 + lr;            // local col 0..127
      bq[nt] = *(const bf16x8*)(lWc +
                 ((wrow * 512 + kk * 64 + g * 16) ^ ((wrow & 7) << 4)));
    }
#pragma unroll
    for (int mt = 0; mt < 4; ++mt)
#pragma unroll
      for (int nt = 0; nt < 4; ++nt)
        acc[mt][nt] = __builtin_amdgcn_mfma_f32_16x16x32_bf16(
            af[mt], bq[nt], acc[mt][nt], 0, 0, 0);
  }

  // ---- epilogue: bias + relu + store (+ register stats) ----
#pragma unroll
  for (int nt = 0; nt < 4; ++nt) {
    const int col = colhalf * 128 + wn * 64 + nt * 16 + lr;
#pragma unroll
    for (int mt = 0; mt < 4; ++mt) {
      f32x4 vv = acc[mt][nt];
      const long rbase = row0 + wm * 64 + mt * 16 + g * 4;
#pragma unroll
      for (int e = 0; e < 4; ++e) {
        const float val = fmaxf(vv[e] + bv[nt], 0.f);
        Out[(rbase + e) * 256 + col] = f2bf(val);
        if (WITH_STATS) {
          if (rbase + e < M) { s[nt] += val; s2[nt] += val * val; }
        }
      }
    }
  }

  if (WITH_STATS) {
#pragma unroll
    for (int nt = 0; nt < 4; ++nt) {
      s[nt]  += __shfl_xor(s[nt], 16);   s2[nt] += __shfl_xor(s2[nt], 16);
      s[nt]  += __shfl_xor(s[nt], 32);   s2[nt] += __shfl_xor(s2[nt], 32);
    }
    if (g == 0) {
      float* p = partials + ((long)blockIdx.x * 4 + wm) * 256;
#pragma unroll
      for (int nt = 0; nt < 4; ++nt) {
        const int cl = wn * 64 + nt * 16 + lr;            // local col 0..127
        p[cl]       = s[nt];
        p[128 + cl] = s2[nt];
      }
    }
  }
}

// ---------------- BN finalize: parallel reduce (one block per column) -------
__global__ __launch_bounds__(256) void bn_finalize_kernel(
    const float* __restrict__ gamma, const float* __restrict__ beta,
    const float* __restrict__ partials, float* __restrict__ stats,
    int M, int ntiles)
{
  __shared__ float red[8];
  const int n  = blockIdx.x;           // column 0..255
  const int t  = threadIdx.x;
  const int ch = n >> 7;
  const int cl = n & 127;
  const int total = ntiles * 4;        // (tile, wm) pairs
  float s = 0.f, s2 = 0.f;
  for (int j = t; j < total; j += 256) {
    const int k  = j >> 2;
    const int wm = j & 3;
    const float* p = partials + ((long)(2 * k + ch) * 4 + wm) * 256;
    s  += p[cl];
    s2 += p[128 + cl];
  }
#pragma unroll
  for (int off = 32; off >= 1; off >>= 1) {
    s  += __shfl_xor(s, off);
    s2 += __shfl_xor(s2, off);
  }
  if ((t & 63) == 0) { red[(t >> 6) * 2] = s; red[(t >> 6) * 2 + 1] = s2; }
  __syncthreads();
  if (t == 0) {
    s  = red[0] + red[2] + red[4] + red[6];
    s2 = red[1] + red[3] + red[5] + red[7];
    const float invM = 1.0f / (float)M;
    const float mean = s * invM;
    float var = s2 * invM - mean * mean;
    var = fmaxf(var, 0.f);
    const float sc = gamma[n] * rsqrtf(var + 1e-5f);
    stats[512 + n] = sc;
    stats[768 + n] = beta[n] - mean * sc;
  }
}

// ---------------- BN normalize: out = h3*scale + shift (8 elems/thread) -----
__global__ __launch_bounds__(256) void bn_norm_kernel(
    const unsigned short* __restrict__ h3, const float* __restrict__ stats,
    float* __restrict__ out, int total8)
{
  const int i = blockIdx.x * 256 + threadIdx.x;
  if (i >= total8) return;
  uint4 v = ((const uint4*)h3)[i];
  const int c = (i * 8) & 255;
  const float4 sc0 = *(const float4*)&stats[512 + c];
  const float4 sc1 = *(const float4*)&stats[516 + c];
  const float4 sh0 = *(const float4*)&stats[768 + c];
  const float4 sh1 = *(const float4*)&stats[772 + c];
  const unsigned short* u = (const unsigned short*)&v;
  float4 o0, o1;
  o0.x = bf2f(u[0]) * sc0.x + sh0.x;
  o0.y = bf2f(u[1]) * sc0.y + sh0.y;
  o0.z = bf2f(u[2]) * sc0.z + sh0.z;
  o0.w = bf2f(u[3]) * sc0.w + sh0.w;
  o1.x = bf2f(u[4]) * sc1.x + sh1.x;
  o1.y = bf2f(u[5]) * sc1.y + sh1.y;
  o1.z = bf2f(u[6]) * sc1.z + sh1.z;
  o1.w = bf2f(u[7]) * sc1.w + sh1.w;
  ((float4*)out)[2 * i]     = o0;
  ((float4*)out)[2 * i + 1] = o1;
}

// ----------------------------------------------------------------------------
extern "C" void kernel_launch(void* const* d_in, const int* in_sizes, int n_in,
                              void* d_out, int out_size, void* d_ws, size_t ws_size,
                              hipStream_t stream) {
  const float* x     = (const float*)d_in[0];
  const int*   nbr   = (const int*)d_in[1];
  const float* W1    = (const float*)d_in[2];
  const float* b1    = (const float*)d_in[3];
  const float* W2    = (const float*)d_in[4];
  const float* b2    = (const float*)d_in[5];
  const float* gamma = (const float*)d_in[6];
  const float* beta  = (const float*)d_in[7];
  const float* alpha_p = (const float*)d_in[8];
  const float* eps_p   = (const float*)d_in[9];
  float* out = (float*)d_out;

  const int  N  = in_sizes[0] / 256;            // 100000
  const long MP = ((long)N + 255) & ~255L;      // padded rows (100096 = 391*256)
  const int  ntiles = (int)(MP / 256);          // 391

  // ws layout: xh (bf16 x -> h2) | bufA (h0 -> h3) | bufB (xq fp8 -> h1) |
  //            Wt1 | Wt2 | h0q (fp8) | partials (2*ntiles*4 rows x 256) | stats
  unsigned short* xh   = (unsigned short*)d_ws;
  unsigned short* bufA = xh + MP * 256;
  unsigned short* bufB = bufA + MP * 256;
  unsigned short* Wt1  = bufB + MP * 256;
  unsigned short* Wt2  = Wt1 + 256 * 256;
  unsigned char*  h0q  = (unsigned char*)(Wt2 + 256 * 256);   // MP*256 bytes
  float* partials = (float*)(h0q + MP * 256);   // 2*ntiles*4*256 floats
  float* stats    = partials + (long)2 * ntiles * 4 * 256;
  unsigned char*  xq = (unsigned char*)bufB;    // aliases bufB (dead before h1)

  x2bf_kernel<<<(N * 32 + 255) / 256, 256, 0, stream>>>(x, xh, xq, N * 32);
  prep_kernel<<<256, 256, 0, stream>>>(W1, W2, Wt1, Wt2);
  aggregate_kernel<<<(N + 3) / 4, 256, 0, stream>>>(xq, nbr, bufA, h0q, N);
  combine_kernel<<<(N + 3) / 4, 256, 0, stream>>>(bufA, h0q, nbr, xh,
                                                  alpha_p, eps_p, bufB, N);

  gemm_w_kernel<0><<<2 * ntiles, 512, 0, stream>>>(bufB, Wt1, b1, xh, nullptr, N);
  gemm_w_kernel<1><<<2 * ntiles, 512, 0, stream>>>(xh, Wt2, b2, bufA, partials, N);

  bn_finalize_kernel<<<256, 256, 0, stream>>>(gamma, beta, partials, stats, N, ntiles);
  bn_norm_kernel<<<(N * 32 + 255) / 256, 256, 0, stream>>>(bufA, stats, out, N * 32);
}

// Round 15
// 303.624 us; speedup vs baseline: 1.0569x; 1.0278x over previous
//
#include <hip/hip_runtime.h>

typedef __bf16 bf16x8 __attribute__((ext_vector_type(8)));
typedef float  f32x4  __attribute__((ext_vector_type(4)));
typedef _Float16 h2v  __attribute__((ext_vector_type(2)));

__device__ __forceinline__ unsigned short f2bf(float f) {
  unsigned u = __builtin_bit_cast(unsigned, f);
  u += 0x7FFFu + ((u >> 16) & 1u);          // round-to-nearest-even
  return (unsigned short)(u >> 16);
}
__device__ __forceinline__ float bf2f(unsigned short b) {
  unsigned u = ((unsigned)b) << 16;
  return __builtin_bit_cast(float, u);
}
__device__ __forceinline__ float bflo(unsigned q) {
  return __builtin_bit_cast(float, q << 16);
}
__device__ __forceinline__ float bfhi(unsigned q) {
  return __builtin_bit_cast(float, q & 0xFFFF0000u);
}
__device__ __forceinline__ unsigned pack2bf(float lo, float hi) {
  return (unsigned)f2bf(lo) | ((unsigned)f2bf(hi) << 16);
}

// ---- fp8 e4m3 bit tricks ----------------------------------------------------
__device__ __forceinline__ float fp8raw(unsigned byte) {   // value * 2^-120
  unsigned b = ((byte & 0x80u) << 24) | ((byte & 0x7Fu) << 20);
  return __builtin_bit_cast(float, b);
}
__device__ __forceinline__ unsigned f2fp8(float v) {       // RNE, |v|<448
  unsigned b = __builtin_bit_cast(unsigned, v);
  unsigned sg = (b >> 24) & 0x80u;
  float a = __builtin_bit_cast(float, b & 0x7FFFFFFFu) * 0x1p-120f;
  unsigned ab = __builtin_bit_cast(unsigned, a);
  ab += 0x7FFFFu + ((ab >> 20) & 1u);
  return sg | ((ab >> 20) & 0x7Fu);
}
// packed decode: word of 4 fp8 bytes -> two f16x2, each f16 = value * 2^-8
__device__ __forceinline__ h2v pkL(unsigned w) {       // (low=e0, high=e2)
  unsigned x = ((w << 8) & 0x80008000u) | ((w << 7) & 0x3F803F80u);
  return __builtin_bit_cast(h2v, x);
}
__device__ __forceinline__ h2v pkH(unsigned w) {       // (low=e1, high=e3)
  unsigned x = (w & 0x80008000u) | ((w >> 1) & 0x3F803F80u);
  return __builtin_bit_cast(h2v, x);
}
__device__ __forceinline__ h2v shfl32(h2v a) {
  return __builtin_bit_cast(h2v,
      __shfl_xor(__builtin_bit_cast(unsigned, a), 32));
}

// ---------------- x -> bf16 + fp8 copies ------------------------------------
__global__ __launch_bounds__(256) void x2bf_kernel(
    const float* __restrict__ x, unsigned short* __restrict__ xh,
    unsigned char* __restrict__ xq, int total8)
{
  const int i = blockIdx.x * 256 + threadIdx.x;
  if (i >= total8) return;
  const float4* p = (const float4*)x + (long)i * 2;
  float4 a = p[0], b = p[1];
  uint4 o;
  o.x = pack2bf(a.x, a.y); o.y = pack2bf(a.z, a.w);
  o.z = pack2bf(b.x, b.y); o.w = pack2bf(b.z, b.w);
  ((uint4*)xh)[i] = o;
  uint2 q;
  q.x = f2fp8(a.x) | (f2fp8(a.y) << 8) | (f2fp8(a.z) << 16) | (f2fp8(a.w) << 24);
  q.y = f2fp8(b.x) | (f2fp8(b.y) << 8) | (f2fp8(b.z) << 16) | (f2fp8(b.w) << 24);
  ((uint2*)xq)[i] = q;
}

// ---------------- prep: W -> Wt (transposed bf16) ----------------------------
__global__ __launch_bounds__(256) void prep_kernel(
    const float* __restrict__ W1, const float* __restrict__ W2,
    unsigned short* __restrict__ Wt1, unsigned short* __restrict__ Wt2)
{
  const int n = blockIdx.x;
  const int k = threadIdx.x;
  Wt1[n * 256 + k] = f2bf(W1[k * 256 + n]);
  Wt2[n * 256 + k] = f2bf(W2[k * 256 + n]);
}

// ------- aggregate: h0 (bf16) + h0q (fp8) = mean over neighbors of xq -------
__global__ __launch_bounds__(256) void aggregate_kernel(
    const unsigned char* __restrict__ xq, const int* __restrict__ nbr,
    unsigned short* __restrict__ h0, unsigned char* __restrict__ h0q, int N)
{
  const int wid  = (blockIdx.x * 256 + threadIdx.x) >> 6;
  const int lane = threadIdx.x & 63;
  if (wid >= N) return;
  const int half = lane >> 5;
  const int l    = lane & 31;
  const unsigned lb = (unsigned)(l << 3);       // lane byte offset in row
  const int* nb = nbr + (long)wid * 16;
  int4 n0 = ((const int4*)nb)[half * 2];
  int4 n1 = ((const int4*)nb)[half * 2 + 1];
  int v[8] = {n0.x, n0.y, n0.z, n0.w, n1.x, n1.y, n1.z, n1.w};
  int mn = v[0];
#pragma unroll
  for (int t = 1; t < 8; ++t) mn = min(mn, v[t]);

  if (__all(mn >= 0)) {                       // fast path: all 16 valid
    uint2 vals[8];
#pragma unroll
    for (int t = 0; t < 8; ++t)
      vals[t] = *(const uint2*)(xq + (((unsigned)v[t] << 8) | lb));
    h2v s02 = (h2v)0, s13 = (h2v)0, s46 = (h2v)0, s57 = (h2v)0;
#pragma unroll
    for (int t = 0; t < 8; ++t) {
      s02 = s02 + pkL(vals[t].x);
      s13 = s13 + pkH(vals[t].x);
      s46 = s46 + pkL(vals[t].y);
      s57 = s57 + pkH(vals[t].y);
    }
    s02 = s02 + shfl32(s02);
    s13 = s13 + shfl32(s13);
    s46 = s46 + shfl32(s46);
    s57 = s57 + shfl32(s57);
    if (half == 0) {
      float m[8];                              // mean = sum * 2^8 / 16
      m[0] = (float)s02[0] * 16.f; m[2] = (float)s02[1] * 16.f;
      m[1] = (float)s13[0] * 16.f; m[3] = (float)s13[1] * 16.f;
      m[4] = (float)s46[0] * 16.f; m[6] = (float)s46[1] * 16.f;
      m[5] = (float)s57[0] * 16.f; m[7] = (float)s57[1] * 16.f;
      uint4 o;
      o.x = pack2bf(m[0], m[1]); o.y = pack2bf(m[2], m[3]);
      o.z = pack2bf(m[4], m[5]); o.w = pack2bf(m[6], m[7]);
      *(uint4*)((char*)h0 + (((unsigned)wid << 9) | (lb << 1))) = o;
      uint2 q;
      q.x = f2fp8(m[0]) | (f2fp8(m[1]) << 8) | (f2fp8(m[2]) << 16) | (f2fp8(m[3]) << 24);
      q.y = f2fp8(m[4]) | (f2fp8(m[5]) << 8) | (f2fp8(m[6]) << 16) | (f2fp8(m[7]) << 24);
      *(uint2*)(h0q + (((unsigned)wid << 8) | lb)) = q;
    }
    return;
  }
  // slow path: masked mean (scalar decode)
  float wgt[8]; int idx[8];
#pragma unroll
  for (int t = 0; t < 8; ++t) {
    wgt[t] = (v[t] >= 0) ? 1.0f : 0.0f;
    idx[t] = (v[t] >= 0) ? v[t] : 0;
  }
  uint2 vals[8];
#pragma unroll
  for (int t = 0; t < 8; ++t)
    vals[t] = *(const uint2*)(xq + (((unsigned)idx[t] << 8) | lb));
  float s[8] = {0.f,0.f,0.f,0.f,0.f,0.f,0.f,0.f};
  float cnt = 0.f;
#pragma unroll
  for (int t = 0; t < 8; ++t) {
    const unsigned w0 = vals[t].x, w1 = vals[t].y;
    cnt += wgt[t];
    s[0] = fmaf(wgt[t], fp8raw(w0 & 0xFF), s[0]);
    s[1] = fmaf(wgt[t], fp8raw((w0 >> 8) & 0xFF), s[1]);
    s[2] = fmaf(wgt[t], fp8raw((w0 >> 16) & 0xFF), s[2]);
    s[3] = fmaf(wgt[t], fp8raw(w0 >> 24), s[3]);
    s[4] = fmaf(wgt[t], fp8raw(w1 & 0xFF), s[4]);
    s[5] = fmaf(wgt[t], fp8raw((w1 >> 8) & 0xFF), s[5]);
    s[6] = fmaf(wgt[t], fp8raw((w1 >> 16) & 0xFF), s[6]);
    s[7] = fmaf(wgt[t], fp8raw(w1 >> 24), s[7]);
  }
#pragma unroll
  for (int e = 0; e < 8; ++e) s[e] += __shfl_xor(s[e], 32);
  cnt += __shfl_xor(cnt, 32);
  const float inv = cnt > 0.f ? 0x1p120f / cnt : 0.f;
  if (half == 0) {
    float m[8];
#pragma unroll
    for (int e = 0; e < 8; ++e) m[e] = s[e] * inv;
    uint4 o;
    o.x = pack2bf(m[0], m[1]); o.y = pack2bf(m[2], m[3]);
    o.z = pack2bf(m[4], m[5]); o.w = pack2bf(m[6], m[7]);
    *(uint4*)((char*)h0 + (((unsigned)wid << 9) | (lb << 1))) = o;
    uint2 q;
    q.x = f2fp8(m[0]) | (f2fp8(m[1]) << 8) | (f2fp8(m[2]) << 16) | (f2fp8(m[3]) << 24);
    q.y = f2fp8(m[4]) | (f2fp8(m[5]) << 8) | (f2fp8(m[6]) << 16) | (f2fp8(m[7]) << 24);
    *(uint2*)(h0q + (((unsigned)wid << 8) | lb)) = q;
  }
}

// ------- combine: h1 = h0 + alpha*maxpool(h0q, nbrs) + (1+eps)*x ------------
__global__ __launch_bounds__(256) void combine_kernel(
    const unsigned short* __restrict__ h0, const unsigned char* __restrict__ h0q,
    const int* __restrict__ nbr, const unsigned short* __restrict__ xh,
    const float* __restrict__ alpha_p, const float* __restrict__ eps_p,
    unsigned short* __restrict__ h1, int N)
{
  const int wid  = (blockIdx.x * 256 + threadIdx.x) >> 6;
  const int lane = threadIdx.x & 63;
  if (wid >= N) return;
  const int half = lane >> 5;
  const int l    = lane & 31;
  const unsigned lb = (unsigned)(l << 3);       // lane byte offset (fp8 row)
  const float alpha = *alpha_p;
  const float c     = 1.0f + *eps_p;
  const int* nb = nbr + (long)wid * 16;
  int4 n0 = ((const int4*)nb)[half * 2];
  int4 n1 = ((const int4*)nb)[half * 2 + 1];
  int v[8] = {n0.x, n0.y, n0.z, n0.w, n1.x, n1.y, n1.z, n1.w};
  int mn = v[0];
#pragma unroll
  for (int t = 1; t < 8; ++t) mn = min(mn, v[t]);

  uint4 own = *(const uint4*)((const char*)h0 + (((unsigned)wid << 9) | (lb << 1)));
  uint4 xv  = *(const uint4*)((const char*)xh + (((unsigned)wid << 9) | (lb << 1)));

  if (__all(mn >= 0)) {                       // fast path: packed f16 max
    uint2 vals[8];
#pragma unroll
    for (int t = 0; t < 8; ++t)
      vals[t] = *(const uint2*)(h0q + (((unsigned)v[t] << 8) | lb));
    const h2v NEG2 = __builtin_bit_cast(h2v, 0xFC00FC00u);   // (-inf,-inf)
    h2v m02 = NEG2, m13 = NEG2, m46 = NEG2, m57 = NEG2;
#pragma unroll
    for (int t = 0; t < 8; ++t) {
      m02 = __builtin_elementwise_max(m02, pkL(vals[t].x));
      m13 = __builtin_elementwise_max(m13, pkH(vals[t].x));
      m46 = __builtin_elementwise_max(m46, pkL(vals[t].y));
      m57 = __builtin_elementwise_max(m57, pkH(vals[t].y));
    }
    m02 = __builtin_elementwise_max(m02, shfl32(m02));
    m13 = __builtin_elementwise_max(m13, shfl32(m13));
    m46 = __builtin_elementwise_max(m46, shfl32(m46));
    m57 = __builtin_elementwise_max(m57, shfl32(m57));
    if (half == 0) {
      float mx[8];                             // true = f16 * 2^8
      mx[0] = (float)m02[0] * 256.f; mx[2] = (float)m02[1] * 256.f;
      mx[1] = (float)m13[0] * 256.f; mx[3] = (float)m13[1] * 256.f;
      mx[4] = (float)m46[0] * 256.f; mx[6] = (float)m46[1] * 256.f;
      mx[5] = (float)m57[0] * 256.f; mx[7] = (float)m57[1] * 256.f;
      const unsigned* qo = (const unsigned*)&own;
      const unsigned* qx = (const unsigned*)&xv;
      uint4 o;
      unsigned* q = (unsigned*)&o;
#pragma unroll
      for (int w = 0; w < 4; ++w) {
        float rl = bflo(qo[w]) + alpha * mx[2*w]   + c * bflo(qx[w]);
        float rh = bfhi(qo[w]) + alpha * mx[2*w+1] + c * bfhi(qx[w]);
        q[w] = pack2bf(rl, rh);
      }
      *(uint4*)((char*)h1 + (((unsigned)wid << 9) | (lb << 1))) = o;
    }
    return;
  }
  // slow path: masked max (scalar decode)
  float mx[8];
#pragma unroll
  for (int e = 0; e < 8; ++e) mx[e] = -3.402823466e38f;
  {
    float wgt[8]; int idx[8];
#pragma unroll
    for (int t = 0; t < 8; ++t) {
      wgt[t] = (v[t] >= 0) ? 1.0f : 0.0f;
      idx[t] = (v[t] >= 0) ? v[t] : 0;
    }
    uint2 vals[8];
#pragma unroll
    for (int t = 0; t < 8; ++t)
      vals[t] = *(const uint2*)(h0q + (((unsigned)idx[t] << 8) | lb));
#pragma unroll
    for (int t = 0; t < 8; ++t) {
      const unsigned w0 = vals[t].x, w1 = vals[t].y;
      const bool valid = wgt[t] > 0.f;
      const float NEG = -3.402823466e38f;
      mx[0] = fmaxf(mx[0], valid ? fp8raw(w0 & 0xFF) * 0x1p120f : NEG);
      mx[1] = fmaxf(mx[1], valid ? fp8raw((w0 >> 8) & 0xFF) * 0x1p120f : NEG);
      mx[2] = fmaxf(mx[2], valid ? fp8raw((w0 >> 16) & 0xFF) * 0x1p120f : NEG);
      mx[3] = fmaxf(mx[3], valid ? fp8raw(w0 >> 24) * 0x1p120f : NEG);
      mx[4] = fmaxf(mx[4], valid ? fp8raw(w1 & 0xFF) * 0x1p120f : NEG);
      mx[5] = fmaxf(mx[5], valid ? fp8raw((w1 >> 8) & 0xFF) * 0x1p120f : NEG);
      mx[6] = fmaxf(mx[6], valid ? fp8raw((w1 >> 16) & 0xFF) * 0x1p120f : NEG);
      mx[7] = fmaxf(mx[7], valid ? fp8raw(w1 >> 24) * 0x1p120f : NEG);
    }
  }
#pragma unroll
  for (int e = 0; e < 8; ++e) mx[e] = fmaxf(mx[e], __shfl_xor(mx[e], 32));
  if (half == 0) {
    const unsigned* qo = (const unsigned*)&own;
    const unsigned* qx = (const unsigned*)&xv;
    uint4 o;
    unsigned* q = (unsigned*)&o;
#pragma unroll
    for (int w = 0; w < 4; ++w) {
      float rl = bflo(qo[w]) + alpha * mx[2*w]   + c * bflo(qx[w]);
      float rh = bfhi(qo[w]) + alpha * mx[2*w+1] + c * bfhi(qx[w]);
      q[w] = pack2bf(rl, rh);
    }
    *(uint4*)((char*)h1 + (((unsigned)wid << 9) | (lb << 1))) = o;
  }
}

// ---------------- half-W-stationary GEMM: Out = relu(A @ W + b) -------------
// 256-row x 128-col tile/block; half of Wt (64 KB) in LDS -> 2 blocks/CU.
// 8 waves = 4 row-groups x 2 col-groups; wave = 64x64, acc[4][4]; per kk:
// 4 global af + 4 LDS bq + 16 MFMA (ratio 4). NEW: epilogue stages C
// fragments through per-wave LDS slices (16 KB) so global stores are
// fully-coalesced 128 B row segments (fixes ~1.9x HBM write amplification
// from scalar 2-byte stores; WRITE_SIZE 96 MB -> ~53 MB expected).
template<int WITH_STATS>
__global__ __launch_bounds__(512, 4) void gemm_w_kernel(
    const unsigned short* __restrict__ A, const unsigned short* __restrict__ Wt,
    const float* __restrict__ bias, unsigned short* __restrict__ Out,
    float* __restrict__ partials, int M)
{
  __shared__ __align__(16) unsigned short lW[128 * 256];   // 64 KB
  __shared__ __align__(16) unsigned short lC[8 * 16 * 64]; // 16 KB (2KB/wave)
  const int tid  = threadIdx.x;
  const int lane = tid & 63;
  const int wave = tid >> 6;          // 0..7
  const int wm   = wave >> 1;         // row group (64 rows each)
  const int wn   = wave & 1;          // col group (64 cols each)
  const int g = lane >> 4, lr = lane & 15;
  const int colhalf = blockIdx.x & 1;
  const long row0   = (long)(blockIdx.x >> 1) * 256;
  char* lWc = (char*)lW;

  // ---- one-time half-W load, XOR-swizzled rows (512 thr x 128 B) ----
  {
    const int row   = tid >> 2;            // 0..127 (local Wt row = out col)
    const int cbase = (tid & 3) * 128;
    const char* src = (const char*)Wt + (long)(colhalf * 128 + row) * 512 + cbase;
#pragma unroll
    for (int i = 0; i < 8; ++i) {
      uint4 v = *(const uint4*)(src + i * 16);
      *(uint4*)(lWc + ((row * 512 + cbase + i * 16) ^ ((row & 7) << 4))) = v;
    }
  }
  __syncthreads();

  float bv[4];
#pragma unroll
  for (int nt = 0; nt < 4; ++nt)
    bv[nt] = bias[colhalf * 128 + wn * 64 + nt * 16 + lr];

  float s[4] = {0.f, 0.f, 0.f, 0.f}, s2[4] = {0.f, 0.f, 0.f, 0.f};
  const char* Ab = (const char*)A;

  f32x4 acc[4][4] = {};
  const long abase = (row0 + wm * 64 + lr) * 512 + g * 16;
#pragma unroll
  for (int kk = 0; kk < 8; ++kk) {
    bf16x8 af[4], bq[4];
#pragma unroll
    for (int mt = 0; mt < 4; ++mt)
      af[mt] = *(const bf16x8*)(Ab + abase + mt * (16 * 512) + kk * 64);
#pragma unroll
    for (int nt = 0; nt < 4; ++nt) {
      const int wrow = wn * 64 + nt * 16 + lr;            // local col 0..127
      bq[nt] = *(const bf16x8*)(lWc +
                 ((wrow * 512 + kk * 64 + g * 16) ^ ((wrow & 7) << 4)));
    }
#pragma unroll
    for (int mt = 0; mt < 4; ++mt)
#pragma unroll
      for (int nt = 0; nt < 4; ++nt)
        acc[mt][nt] = __builtin_amdgcn_mfma_f32_16x16x32_bf16(
            af[mt], bq[nt], acc[mt][nt], 0, 0, 0);
  }

  // ---- epilogue: bias + relu -> per-wave LDS slice -> coalesced stores ----
  unsigned short* myC = lC + wave * (16 * 64);
#pragma unroll
  for (int mt = 0; mt < 4; ++mt) {
#pragma unroll
    for (int nt = 0; nt < 4; ++nt) {
      f32x4 vv = acc[mt][nt];
#pragma unroll
      for (int e = 0; e < 4; ++e) {
        const float val = fmaxf(vv[e] + bv[nt], 0.f);
        myC[(g * 4 + e) * 64 + nt * 16 + lr] = f2bf(val);
        if (WITH_STATS) {
          const long row = row0 + wm * 64 + mt * 16 + g * 4 + e;
          if (row < M) { s[nt] += val; s2[nt] += val * val; }
        }
      }
    }
    __asm__ volatile("s_waitcnt lgkmcnt(0)" ::: "memory");
    // read back 16 rows x 128 B, store coalesced (whole cache lines)
    const int rrow = lane >> 3;        // 0..7
    const int rchk = lane & 7;         // 0..7 chunks of 16 B
#pragma unroll
    for (int h = 0; h < 2; ++h) {
      const int lrow = h * 8 + rrow;
      uint4 vv = *(const uint4*)(myC + lrow * 64 + rchk * 8);
      const long grow = row0 + wm * 64 + mt * 16 + lrow;
      *(uint4*)((char*)Out + grow * 512 + colhalf * 256 + wn * 128 + rchk * 16) = vv;
    }
    __asm__ volatile("s_waitcnt vmcnt(0)" ::: "memory");   // slice reuse safety
  }

  if (WITH_STATS) {
#pragma unroll
    for (int nt = 0; nt < 4; ++nt) {
      s[nt]  += __shfl_xor(s[nt], 16);   s2[nt] += __shfl_xor(s2[nt], 16);
      s[nt]  += __shfl_xor(s[nt], 32);   s2[nt] += __shfl_xor(s2[nt], 32);
    }
    if (g == 0) {
      float* p = partials + ((long)blockIdx.x * 4 + wm) * 256;
#pragma unroll
      for (int nt = 0; nt < 4; ++nt) {
        const int cl = wn * 64 + nt * 16 + lr;            // local col 0..127
        p[cl]       = s[nt];
        p[128 + cl] = s2[nt];
      }
    }
  }
}

// ---------------- BN finalize: parallel reduce (one block per column) -------
__global__ __launch_bounds__(256) void bn_finalize_kernel(
    const float* __restrict__ gamma, const float* __restrict__ beta,
    const float* __restrict__ partials, float* __restrict__ stats,
    int M, int ntiles)
{
  __shared__ float red[8];
  const int n  = blockIdx.x;           // column 0..255
  const int t  = threadIdx.x;
  const int ch = n >> 7;
  const int cl = n & 127;
  const int total = ntiles * 4;        // (tile, wm) pairs
  float s = 0.f, s2 = 0.f;
  for (int j = t; j < total; j += 256) {
    const int k  = j >> 2;
    const int wm = j & 3;
    const float* p = partials + ((long)(2 * k + ch) * 4 + wm) * 256;
    s  += p[cl];
    s2 += p[128 + cl];
  }
#pragma unroll
  for (int off = 32; off >= 1; off >>= 1) {
    s  += __shfl_xor(s, off);
    s2 += __shfl_xor(s2, off);
  }
  if ((t & 63) == 0) { red[(t >> 6) * 2] = s; red[(t >> 6) * 2 + 1] = s2; }
  __syncthreads();
  if (t == 0) {
    s  = red[0] + red[2] + red[4] + red[6];
    s2 = red[1] + red[3] + red[5] + red[7];
    const float invM = 1.0f / (float)M;
    const float mean = s * invM;
    float var = s2 * invM - mean * mean;
    var = fmaxf(var, 0.f);
    const float sc = gamma[n] * rsqrtf(var + 1e-5f);
    stats[512 + n] = sc;
    stats[768 + n] = beta[n] - mean * sc;
  }
}

// ---------------- BN normalize: out = h3*scale + shift (8 elems/thread) -----
__global__ __launch_bounds__(256) void bn_norm_kernel(
    const unsigned short* __restrict__ h3, const float* __restrict__ stats,
    float* __restrict__ out, int total8)
{
  const int i = blockIdx.x * 256 + threadIdx.x;
  if (i >= total8) return;
  uint4 v = ((const uint4*)h3)[i];
  const int c = (i * 8) & 255;
  const float4 sc0 = *(const float4*)&stats[512 + c];
  const float4 sc1 = *(const float4*)&stats[516 + c];
  const float4 sh0 = *(const float4*)&stats[768 + c];
  const float4 sh1 = *(const float4*)&stats[772 + c];
  const unsigned short* u = (const unsigned short*)&v;
  float4 o0, o1;
  o0.x = bf2f(u[0]) * sc0.x + sh0.x;
  o0.y = bf2f(u[1]) * sc0.y + sh0.y;
  o0.z = bf2f(u[2]) * sc0.z + sh0.z;
  o0.w = bf2f(u[3]) * sc0.w + sh0.w;
  o1.x = bf2f(u[4]) * sc1.x + sh1.x;
  o1.y = bf2f(u[5]) * sc1.y + sh1.y;
  o1.z = bf2f(u[6]) * sc1.z + sh1.z;
  o1.w = bf2f(u[7]) * sc1.w + sh1.w;
  ((float4*)out)[2 * i]     = o0;
  ((float4*)out)[2 * i + 1] = o1;
}

// ----------------------------------------------------------------------------
extern "C" void kernel_launch(void* const* d_in, const int* in_sizes, int n_in,
                              void* d_out, int out_size, void* d_ws, size_t ws_size,
                              hipStream_t stream) {
  const float* x     = (const float*)d_in[0];
  const int*   nbr   = (const int*)d_in[1];
  const float* W1    = (const float*)d_in[2];
  const float* b1    = (const float*)d_in[3];
  const float* W2    = (const float*)d_in[4];
  const float* b2    = (const float*)d_in[5];
  const float* gamma = (const float*)d_in[6];
  const float* beta  = (const float*)d_in[7];
  const float* alpha_p = (const float*)d_in[8];
  const float* eps_p   = (const float*)d_in[9];
  float* out = (float*)d_out;

  const int  N  = in_sizes[0] / 256;            // 100000
  const long MP = ((long)N + 255) & ~255L;      // padded rows (100096 = 391*256)
  const int  ntiles = (int)(MP / 256);          // 391

  // ws layout: xh (bf16 x -> h2) | bufA (h0 -> h3) | bufB (xq fp8 -> h1) |
  //            Wt1 | Wt2 | h0q (fp8) | partials (2*ntiles*4 rows x 256) | stats
  unsigned short* xh   = (unsigned short*)d_ws;
  unsigned short* bufA = xh + MP * 256;
  unsigned short* bufB = bufA + MP * 256;
  unsigned short* Wt1  = bufB + MP * 256;
  unsigned short* Wt2  = Wt1 + 256 * 256;
  unsigned char*  h0q  = (unsigned char*)(Wt2 + 256 * 256);   // MP*256 bytes
  float* partials = (float*)(h0q + MP * 256);   // 2*ntiles*4*256 floats
  float* stats    = partials + (long)2 * ntiles * 4 * 256;
  unsigned char*  xq = (unsigned char*)bufB;    // aliases bufB (dead before h1)

  x2bf_kernel<<<(N * 32 + 255) / 256, 256, 0, stream>>>(x, xh, xq, N * 32);
  prep_kernel<<<256, 256, 0, stream>>>(W1, W2, Wt1, Wt2);
  aggregate_kernel<<<(N + 3) / 4, 256, 0, stream>>>(xq, nbr, bufA, h0q, N);
  combine_kernel<<<(N + 3) / 4, 256, 0, stream>>>(bufA, h0q, nbr, xh,
                                                  alpha_p, eps_p, bufB, N);

  gemm_w_kernel<0><<<2 * ntiles, 512, 0, stream>>>(bufB, Wt1, b1, xh, nullptr, N);
  gemm_w_kernel<1><<<2 * ntiles, 512, 0, stream>>>(xh, Wt2, b2, bufA, partials, N);

  bn_finalize_kernel<<<256, 256, 0, stream>>>(gamma, beta, partials, stats, N, ntiles);
  bn_norm_kernel<<<(N * 32 + 255) / 256, 256, 0, stream>>>(bufA, stats, out, N * 32);
}

// Round 16
// 299.923 us; speedup vs baseline: 1.0699x; 1.0123x over previous
//
#include <hip/hip_runtime.h>

typedef __bf16 bf16x8 __attribute__((ext_vector_type(8)));
typedef float  f32x4  __attribute__((ext_vector_type(4)));
typedef _Float16 h2v  __attribute__((ext_vector_type(2)));

__device__ __forceinline__ unsigned short f2bf(float f) {
  unsigned u = __builtin_bit_cast(unsigned, f);
  u += 0x7FFFu + ((u >> 16) & 1u);          // round-to-nearest-even
  return (unsigned short)(u >> 16);
}
__device__ __forceinline__ float bf2f(unsigned short b) {
  unsigned u = ((unsigned)b) << 16;
  return __builtin_bit_cast(float, u);
}
__device__ __forceinline__ float bflo(unsigned q) {
  return __builtin_bit_cast(float, q << 16);
}
__device__ __forceinline__ float bfhi(unsigned q) {
  return __builtin_bit_cast(float, q & 0xFFFF0000u);
}
__device__ __forceinline__ unsigned pack2bf(float lo, float hi) {
  return (unsigned)f2bf(lo) | ((unsigned)f2bf(hi) << 16);
}

// ---- fp8 e4m3 bit tricks ----------------------------------------------------
__device__ __forceinline__ float fp8raw(unsigned byte) {   // value * 2^-120
  unsigned b = ((byte & 0x80u) << 24) | ((byte & 0x7Fu) << 20);
  return __builtin_bit_cast(float, b);
}
__device__ __forceinline__ unsigned f2fp8(float v) {       // RNE, |v|<448
  unsigned b = __builtin_bit_cast(unsigned, v);
  unsigned sg = (b >> 24) & 0x80u;
  float a = __builtin_bit_cast(float, b & 0x7FFFFFFFu) * 0x1p-120f;
  unsigned ab = __builtin_bit_cast(unsigned, a);
  ab += 0x7FFFFu + ((ab >> 20) & 1u);
  return sg | ((ab >> 20) & 0x7Fu);
}
// packed decode: word of 4 fp8 bytes -> two f16x2, each f16 = value * 2^-8
__device__ __forceinline__ h2v pkL(unsigned w) {       // (low=e0, high=e2)
  unsigned x = ((w << 8) & 0x80008000u) | ((w << 7) & 0x3F803F80u);
  return __builtin_bit_cast(h2v, x);
}
__device__ __forceinline__ h2v pkH(unsigned w) {       // (low=e1, high=e3)
  unsigned x = (w & 0x80008000u) | ((w >> 1) & 0x3F803F80u);
  return __builtin_bit_cast(h2v, x);
}
__device__ __forceinline__ h2v shfl32(h2v a) {
  return __builtin_bit_cast(h2v,
      __shfl_xor(__builtin_bit_cast(unsigned, a), 32));
}

// ---------------- x -> bf16 + fp8 copies ------------------------------------
__global__ __launch_bounds__(256) void x2bf_kernel(
    const float* __restrict__ x, unsigned short* __restrict__ xh,
    unsigned char* __restrict__ xq, int total8)
{
  const int i = blockIdx.x * 256 + threadIdx.x;
  if (i >= total8) return;
  const float4* p = (const float4*)x + (long)i * 2;
  float4 a = p[0], b = p[1];
  uint4 o;
  o.x = pack2bf(a.x, a.y); o.y = pack2bf(a.z, a.w);
  o.z = pack2bf(b.x, b.y); o.w = pack2bf(b.z, b.w);
  ((uint4*)xh)[i] = o;
  uint2 q;
  q.x = f2fp8(a.x) | (f2fp8(a.y) << 8) | (f2fp8(a.z) << 16) | (f2fp8(a.w) << 24);
  q.y = f2fp8(b.x) | (f2fp8(b.y) << 8) | (f2fp8(b.z) << 16) | (f2fp8(b.w) << 24);
  ((uint2*)xq)[i] = q;
}

// ---------------- prep: W -> Wt (transposed bf16) ----------------------------
__global__ __launch_bounds__(256) void prep_kernel(
    const float* __restrict__ W1, const float* __restrict__ W2,
    unsigned short* __restrict__ Wt1, unsigned short* __restrict__ Wt2)
{
  const int n = blockIdx.x;
  const int k = threadIdx.x;
  Wt1[n * 256 + k] = f2bf(W1[k * 256 + n]);
  Wt2[n * 256 + k] = f2bf(W2[k * 256 + n]);
}

// ------- aggregate: h0 (bf16) + h0q (fp8) = mean over neighbors of xq -------
__global__ __launch_bounds__(256) void aggregate_kernel(
    const unsigned char* __restrict__ xq, const int* __restrict__ nbr,
    unsigned short* __restrict__ h0, unsigned char* __restrict__ h0q, int N)
{
  const int wid  = (blockIdx.x * 256 + threadIdx.x) >> 6;
  const int lane = threadIdx.x & 63;
  if (wid >= N) return;
  const int half = lane >> 5;
  const int l    = lane & 31;
  const unsigned lb = (unsigned)(l << 3);       // lane byte offset in row
  const int* nb = nbr + (long)wid * 16;
  int4 n0 = ((const int4*)nb)[half * 2];
  int4 n1 = ((const int4*)nb)[half * 2 + 1];
  int v[8] = {n0.x, n0.y, n0.z, n0.w, n1.x, n1.y, n1.z, n1.w};
  int mn = v[0];
#pragma unroll
  for (int t = 1; t < 8; ++t) mn = min(mn, v[t]);

  if (__all(mn >= 0)) {                       // fast path: all 16 valid
    uint2 vals[8];
#pragma unroll
    for (int t = 0; t < 8; ++t)
      vals[t] = *(const uint2*)(xq + (((unsigned)v[t] << 8) | lb));
    h2v s02 = (h2v)0, s13 = (h2v)0, s46 = (h2v)0, s57 = (h2v)0;
#pragma unroll
    for (int t = 0; t < 8; ++t) {
      s02 = s02 + pkL(vals[t].x);
      s13 = s13 + pkH(vals[t].x);
      s46 = s46 + pkL(vals[t].y);
      s57 = s57 + pkH(vals[t].y);
    }
    s02 = s02 + shfl32(s02);
    s13 = s13 + shfl32(s13);
    s46 = s46 + shfl32(s46);
    s57 = s57 + shfl32(s57);
    if (half == 0) {
      float m[8];                              // mean = sum * 2^8 / 16
      m[0] = (float)s02[0] * 16.f; m[2] = (float)s02[1] * 16.f;
      m[1] = (float)s13[0] * 16.f; m[3] = (float)s13[1] * 16.f;
      m[4] = (float)s46[0] * 16.f; m[6] = (float)s46[1] * 16.f;
      m[5] = (float)s57[0] * 16.f; m[7] = (float)s57[1] * 16.f;
      uint4 o;
      o.x = pack2bf(m[0], m[1]); o.y = pack2bf(m[2], m[3]);
      o.z = pack2bf(m[4], m[5]); o.w = pack2bf(m[6], m[7]);
      *(uint4*)((char*)h0 + (((unsigned)wid << 9) | (lb << 1))) = o;
      uint2 q;
      q.x = f2fp8(m[0]) | (f2fp8(m[1]) << 8) | (f2fp8(m[2]) << 16) | (f2fp8(m[3]) << 24);
      q.y = f2fp8(m[4]) | (f2fp8(m[5]) << 8) | (f2fp8(m[6]) << 16) | (f2fp8(m[7]) << 24);
      *(uint2*)(h0q + (((unsigned)wid << 8) | lb)) = q;
    }
    return;
  }
  // slow path: masked mean (scalar decode)
  float wgt[8]; int idx[8];
#pragma unroll
  for (int t = 0; t < 8; ++t) {
    wgt[t] = (v[t] >= 0) ? 1.0f : 0.0f;
    idx[t] = (v[t] >= 0) ? v[t] : 0;
  }
  uint2 vals[8];
#pragma unroll
  for (int t = 0; t < 8; ++t)
    vals[t] = *(const uint2*)(xq + (((unsigned)idx[t] << 8) | lb));
  float s[8] = {0.f,0.f,0.f,0.f,0.f,0.f,0.f,0.f};
  float cnt = 0.f;
#pragma unroll
  for (int t = 0; t < 8; ++t) {
    const unsigned w0 = vals[t].x, w1 = vals[t].y;
    cnt += wgt[t];
    s[0] = fmaf(wgt[t], fp8raw(w0 & 0xFF), s[0]);
    s[1] = fmaf(wgt[t], fp8raw((w0 >> 8) & 0xFF), s[1]);
    s[2] = fmaf(wgt[t], fp8raw((w0 >> 16) & 0xFF), s[2]);
    s[3] = fmaf(wgt[t], fp8raw(w0 >> 24), s[3]);
    s[4] = fmaf(wgt[t], fp8raw(w1 & 0xFF), s[4]);
    s[5] = fmaf(wgt[t], fp8raw((w1 >> 8) & 0xFF), s[5]);
    s[6] = fmaf(wgt[t], fp8raw((w1 >> 16) & 0xFF), s[6]);
    s[7] = fmaf(wgt[t], fp8raw(w1 >> 24), s[7]);
  }
#pragma unroll
  for (int e = 0; e < 8; ++e) s[e] += __shfl_xor(s[e], 32);
  cnt += __shfl_xor(cnt, 32);
  const float inv = cnt > 0.f ? 0x1p120f / cnt : 0.f;
  if (half == 0) {
    float m[8];
#pragma unroll
    for (int e = 0; e < 8; ++e) m[e] = s[e] * inv;
    uint4 o;
    o.x = pack2bf(m[0], m[1]); o.y = pack2bf(m[2], m[3]);
    o.z = pack2bf(m[4], m[5]); o.w = pack2bf(m[6], m[7]);
    *(uint4*)((char*)h0 + (((unsigned)wid << 9) | (lb << 1))) = o;
    uint2 q;
    q.x = f2fp8(m[0]) | (f2fp8(m[1]) << 8) | (f2fp8(m[2]) << 16) | (f2fp8(m[3]) << 24);
    q.y = f2fp8(m[4]) | (f2fp8(m[5]) << 8) | (f2fp8(m[6]) << 16) | (f2fp8(m[7]) << 24);
    *(uint2*)(h0q + (((unsigned)wid << 8) | lb)) = q;
  }
}

// ------- combine: h1 = h0 + alpha*maxpool(h0q, nbrs) + (1+eps)*x ------------
__global__ __launch_bounds__(256) void combine_kernel(
    const unsigned short* __restrict__ h0, const unsigned char* __restrict__ h0q,
    const int* __restrict__ nbr, const unsigned short* __restrict__ xh,
    const float* __restrict__ alpha_p, const float* __restrict__ eps_p,
    unsigned short* __restrict__ h1, int N)
{
  const int wid  = (blockIdx.x * 256 + threadIdx.x) >> 6;
  const int lane = threadIdx.x & 63;
  if (wid >= N) return;
  const int half = lane >> 5;
  const int l    = lane & 31;
  const unsigned lb = (unsigned)(l << 3);       // lane byte offset (fp8 row)
  const float alpha = *alpha_p;
  const float c     = 1.0f + *eps_p;
  const int* nb = nbr + (long)wid * 16;
  int4 n0 = ((const int4*)nb)[half * 2];
  int4 n1 = ((const int4*)nb)[half * 2 + 1];
  int v[8] = {n0.x, n0.y, n0.z, n0.w, n1.x, n1.y, n1.z, n1.w};
  int mn = v[0];
#pragma unroll
  for (int t = 1; t < 8; ++t) mn = min(mn, v[t]);

  uint4 own = *(const uint4*)((const char*)h0 + (((unsigned)wid << 9) | (lb << 1)));
  uint4 xv  = *(const uint4*)((const char*)xh + (((unsigned)wid << 9) | (lb << 1)));

  if (__all(mn >= 0)) {                       // fast path: packed f16 max
    uint2 vals[8];
#pragma unroll
    for (int t = 0; t < 8; ++t)
      vals[t] = *(const uint2*)(h0q + (((unsigned)v[t] << 8) | lb));
    const h2v NEG2 = __builtin_bit_cast(h2v, 0xFC00FC00u);   // (-inf,-inf)
    h2v m02 = NEG2, m13 = NEG2, m46 = NEG2, m57 = NEG2;
#pragma unroll
    for (int t = 0; t < 8; ++t) {
      m02 = __builtin_elementwise_max(m02, pkL(vals[t].x));
      m13 = __builtin_elementwise_max(m13, pkH(vals[t].x));
      m46 = __builtin_elementwise_max(m46, pkL(vals[t].y));
      m57 = __builtin_elementwise_max(m57, pkH(vals[t].y));
    }
    m02 = __builtin_elementwise_max(m02, shfl32(m02));
    m13 = __builtin_elementwise_max(m13, shfl32(m13));
    m46 = __builtin_elementwise_max(m46, shfl32(m46));
    m57 = __builtin_elementwise_max(m57, shfl32(m57));
    if (half == 0) {
      float mx[8];                             // true = f16 * 2^8
      mx[0] = (float)m02[0] * 256.f; mx[2] = (float)m02[1] * 256.f;
      mx[1] = (float)m13[0] * 256.f; mx[3] = (float)m13[1] * 256.f;
      mx[4] = (float)m46[0] * 256.f; mx[6] = (float)m46[1] * 256.f;
      mx[5] = (float)m57[0] * 256.f; mx[7] = (float)m57[1] * 256.f;
      const unsigned* qo = (const unsigned*)&own;
      const unsigned* qx = (const unsigned*)&xv;
      uint4 o;
      unsigned* q = (unsigned*)&o;
#pragma unroll
      for (int w = 0; w < 4; ++w) {
        float rl = bflo(qo[w]) + alpha * mx[2*w]   + c * bflo(qx[w]);
        float rh = bfhi(qo[w]) + alpha * mx[2*w+1] + c * bfhi(qx[w]);
        q[w] = pack2bf(rl, rh);
      }
      *(uint4*)((char*)h1 + (((unsigned)wid << 9) | (lb << 1))) = o;
    }
    return;
  }
  // slow path: masked max (scalar decode)
  float mx[8];
#pragma unroll
  for (int e = 0; e < 8; ++e) mx[e] = -3.402823466e38f;
  {
    float wgt[8]; int idx[8];
#pragma unroll
    for (int t = 0; t < 8; ++t) {
      wgt[t] = (v[t] >= 0) ? 1.0f : 0.0f;
      idx[t] = (v[t] >= 0) ? v[t] : 0;
    }
    uint2 vals[8];
#pragma unroll
    for (int t = 0; t < 8; ++t)
      vals[t] = *(const uint2*)(h0q + (((unsigned)idx[t] << 8) | lb));
#pragma unroll
    for (int t = 0; t < 8; ++t) {
      const unsigned w0 = vals[t].x, w1 = vals[t].y;
      const bool valid = wgt[t] > 0.f;
      const float NEG = -3.402823466e38f;
      mx[0] = fmaxf(mx[0], valid ? fp8raw(w0 & 0xFF) * 0x1p120f : NEG);
      mx[1] = fmaxf(mx[1], valid ? fp8raw((w0 >> 8) & 0xFF) * 0x1p120f : NEG);
      mx[2] = fmaxf(mx[2], valid ? fp8raw((w0 >> 16) & 0xFF) * 0x1p120f : NEG);
      mx[3] = fmaxf(mx[3], valid ? fp8raw(w0 >> 24) * 0x1p120f : NEG);
      mx[4] = fmaxf(mx[4], valid ? fp8raw(w1 & 0xFF) * 0x1p120f : NEG);
      mx[5] = fmaxf(mx[5], valid ? fp8raw((w1 >> 8) & 0xFF) * 0x1p120f : NEG);
      mx[6] = fmaxf(mx[6], valid ? fp8raw((w1 >> 16) & 0xFF) * 0x1p120f : NEG);
      mx[7] = fmaxf(mx[7], valid ? fp8raw(w1 >> 24) * 0x1p120f : NEG);
    }
  }
#pragma unroll
  for (int e = 0; e < 8; ++e) mx[e] = fmaxf(mx[e], __shfl_xor(mx[e], 32));
  if (half == 0) {
    const unsigned* qo = (const unsigned*)&own;
    const unsigned* qx = (const unsigned*)&xv;
    uint4 o;
    unsigned* q = (unsigned*)&o;
#pragma unroll
    for (int w = 0; w < 4; ++w) {
      float rl = bflo(qo[w]) + alpha * mx[2*w]   + c * bflo(qx[w]);
      float rh = bfhi(qo[w]) + alpha * mx[2*w+1] + c * bfhi(qx[w]);
      q[w] = pack2bf(rl, rh);
    }
    *(uint4*)((char*)h1 + (((unsigned)wid << 9) | (lb << 1))) = o;
  }
}

// ---------------- half-W-stationary GEMM: Out = relu(A @ W + b) -------------
// 256-row x 128-col tile/block; half of Wt (64 KB) in LDS -> 2 blocks/CU.
// 8 waves = 4 row-groups x 2 col-groups; wave = 64x64, acc[4][4]; per kk:
// 4 global af + 4 LDS bq + 16 MFMA (ratio 4). Coalesced LDS-staged C stores.
// NEW: bijective XCD swizzle (m204) so colhalf pairs + neighbor tiles share
// one XCD L2 (A-tile fetched once per XCD, not twice).
template<int WITH_STATS>
__global__ __launch_bounds__(512, 4) void gemm_w_kernel(
    const unsigned short* __restrict__ A, const unsigned short* __restrict__ Wt,
    const float* __restrict__ bias, unsigned short* __restrict__ Out,
    float* __restrict__ partials, int M, int nwg)
{
  __shared__ __align__(16) unsigned short lW[128 * 256];   // 64 KB
  __shared__ __align__(16) unsigned short lC[8 * 16 * 64]; // 16 KB (2KB/wave)
  const int tid  = threadIdx.x;
  const int lane = tid & 63;
  const int wave = tid >> 6;          // 0..7
  const int wm   = wave >> 1;         // row group (64 rows each)
  const int wn   = wave & 1;          // col group (64 cols each)
  const int g = lane >> 4, lr = lane & 15;

  // bijective XCD swizzle: orig%8 = physical XCD -> contiguous wgid chunk
  const int q8 = nwg >> 3, r8 = nwg & 7;
  const int orig = blockIdx.x;
  const int xcd = orig & 7, loc = orig >> 3;
  const int wgid = (xcd < r8 ? xcd * (q8 + 1) : r8 * (q8 + 1) + (xcd - r8) * q8) + loc;

  const int colhalf = wgid & 1;
  const long row0   = (long)(wgid >> 1) * 256;
  char* lWc = (char*)lW;

  // ---- one-time half-W load, XOR-swizzled rows (512 thr x 128 B) ----
  {
    const int row   = tid >> 2;            // 0..127 (local Wt row = out col)
    const int cbase = (tid & 3) * 128;
    const char* src = (const char*)Wt + (long)(colhalf * 128 + row) * 512 + cbase;
#pragma unroll
    for (int i = 0; i < 8; ++i) {
      uint4 v = *(const uint4*)(src + i * 16);
      *(uint4*)(lWc + ((row * 512 + cbase + i * 16) ^ ((row & 7) << 4))) = v;
    }
  }
  __syncthreads();

  float bv[4];
#pragma unroll
  for (int nt = 0; nt < 4; ++nt)
    bv[nt] = bias[colhalf * 128 + wn * 64 + nt * 16 + lr];

  float s[4] = {0.f, 0.f, 0.f, 0.f}, s2[4] = {0.f, 0.f, 0.f, 0.f};
  const char* Ab = (const char*)A;

  f32x4 acc[4][4] = {};
  const long abase = (row0 + wm * 64 + lr) * 512 + g * 16;
#pragma unroll
  for (int kk = 0; kk < 8; ++kk) {
    bf16x8 af[4], bq[4];
#pragma unroll
    for (int mt = 0; mt < 4; ++mt)
      af[mt] = *(const bf16x8*)(Ab + abase + mt * (16 * 512) + kk * 64);
#pragma unroll
    for (int nt = 0; nt < 4; ++nt) {
      const int wrow = wn * 64 + nt * 16 + lr;            // local col 0..127
      bq[nt] = *(const bf16x8*)(lWc +
                 ((wrow * 512 + kk * 64 + g * 16) ^ ((wrow & 7) << 4)));
    }
#pragma unroll
    for (int mt = 0; mt < 4; ++mt)
#pragma unroll
      for (int nt = 0; nt < 4; ++nt)
        acc[mt][nt] = __builtin_amdgcn_mfma_f32_16x16x32_bf16(
            af[mt], bq[nt], acc[mt][nt], 0, 0, 0);
  }

  // ---- epilogue: bias + relu -> per-wave LDS slice -> coalesced stores ----
  unsigned short* myC = lC + wave * (16 * 64);
#pragma unroll
  for (int mt = 0; mt < 4; ++mt) {
#pragma unroll
    for (int nt = 0; nt < 4; ++nt) {
      f32x4 vv = acc[mt][nt];
#pragma unroll
      for (int e = 0; e < 4; ++e) {
        const float val = fmaxf(vv[e] + bv[nt], 0.f);
        myC[(g * 4 + e) * 64 + nt * 16 + lr] = f2bf(val);
        if (WITH_STATS) {
          const long row = row0 + wm * 64 + mt * 16 + g * 4 + e;
          if (row < M) { s[nt] += val; s2[nt] += val * val; }
        }
      }
    }
    __asm__ volatile("s_waitcnt lgkmcnt(0)" ::: "memory");
    const int rrow = lane >> 3;        // 0..7
    const int rchk = lane & 7;         // 0..7 chunks of 16 B
#pragma unroll
    for (int h = 0; h < 2; ++h) {
      const int lrow = h * 8 + rrow;
      uint4 vv = *(const uint4*)(myC + lrow * 64 + rchk * 8);
      const long grow = row0 + wm * 64 + mt * 16 + lrow;
      *(uint4*)((char*)Out + grow * 512 + colhalf * 256 + wn * 128 + rchk * 16) = vv;
    }
    __asm__ volatile("s_waitcnt vmcnt(0)" ::: "memory");   // slice reuse safety
  }

  if (WITH_STATS) {
#pragma unroll
    for (int nt = 0; nt < 4; ++nt) {
      s[nt]  += __shfl_xor(s[nt], 16);   s2[nt] += __shfl_xor(s2[nt], 16);
      s[nt]  += __shfl_xor(s[nt], 32);   s2[nt] += __shfl_xor(s2[nt], 32);
    }
    if (g == 0) {
      float* p = partials + ((long)wgid * 4 + wm) * 256;
#pragma unroll
      for (int nt = 0; nt < 4; ++nt) {
        const int cl = wn * 64 + nt * 16 + lr;            // local col 0..127
        p[cl]       = s[nt];
        p[128 + cl] = s2[nt];
      }
    }
  }
}

// ---------------- BN finalize: parallel reduce (one block per column) -------
__global__ __launch_bounds__(256) void bn_finalize_kernel(
    const float* __restrict__ gamma, const float* __restrict__ beta,
    const float* __restrict__ partials, float* __restrict__ stats,
    int M, int ntiles)
{
  __shared__ float red[8];
  const int n  = blockIdx.x;           // column 0..255
  const int t  = threadIdx.x;
  const int ch = n >> 7;
  const int cl = n & 127;
  const int total = ntiles * 4;        // (tile, wm) pairs
  float s = 0.f, s2 = 0.f;
  for (int j = t; j < total; j += 256) {
    const int k  = j >> 2;
    const int wm = j & 3;
    const float* p = partials + ((long)(2 * k + ch) * 4 + wm) * 256;
    s  += p[cl];
    s2 += p[128 + cl];
  }
#pragma unroll
  for (int off = 32; off >= 1; off >>= 1) {
    s  += __shfl_xor(s, off);
    s2 += __shfl_xor(s2, off);
  }
  if ((t & 63) == 0) { red[(t >> 6) * 2] = s; red[(t >> 6) * 2 + 1] = s2; }
  __syncthreads();
  if (t == 0) {
    s  = red[0] + red[2] + red[4] + red[6];
    s2 = red[1] + red[3] + red[5] + red[7];
    const float invM = 1.0f / (float)M;
    const float mean = s * invM;
    float var = s2 * invM - mean * mean;
    var = fmaxf(var, 0.f);
    const float sc = gamma[n] * rsqrtf(var + 1e-5f);
    stats[512 + n] = sc;
    stats[768 + n] = beta[n] - mean * sc;
  }
}

// ---------------- BN normalize: out = h3*scale + shift (8 elems/thread) -----
__global__ __launch_bounds__(256) void bn_norm_kernel(
    const unsigned short* __restrict__ h3, const float* __restrict__ stats,
    float* __restrict__ out, int total8)
{
  const int i = blockIdx.x * 256 + threadIdx.x;
  if (i >= total8) return;
  uint4 v = ((const uint4*)h3)[i];
  const int c = (i * 8) & 255;
  const float4 sc0 = *(const float4*)&stats[512 + c];
  const float4 sc1 = *(const float4*)&stats[516 + c];
  const float4 sh0 = *(const float4*)&stats[768 + c];
  const float4 sh1 = *(const float4*)&stats[772 + c];
  const unsigned short* u = (const unsigned short*)&v;
  float4 o0, o1;
  o0.x = bf2f(u[0]) * sc0.x + sh0.x;
  o0.y = bf2f(u[1]) * sc0.y + sh0.y;
  o0.z = bf2f(u[2]) * sc0.z + sh0.z;
  o0.w = bf2f(u[3]) * sc0.w + sh0.w;
  o1.x = bf2f(u[4]) * sc1.x + sh1.x;
  o1.y = bf2f(u[5]) * sc1.y + sh1.y;
  o1.z = bf2f(u[6]) * sc1.z + sh1.z;
  o1.w = bf2f(u[7]) * sc1.w + sh1.w;
  ((float4*)out)[2 * i]     = o0;
  ((float4*)out)[2 * i + 1] = o1;
}

// ----------------------------------------------------------------------------
extern "C" void kernel_launch(void* const* d_in, const int* in_sizes, int n_in,
                              void* d_out, int out_size, void* d_ws, size_t ws_size,
                              hipStream_t stream) {
  const float* x     = (const float*)d_in[0];
  const int*   nbr   = (const int*)d_in[1];
  const float* W1    = (const float*)d_in[2];
  const float* b1    = (const float*)d_in[3];
  const float* W2    = (const float*)d_in[4];
  const float* b2    = (const float*)d_in[5];
  const float* gamma = (const float*)d_in[6];
  const float* beta  = (const float*)d_in[7];
  const float* alpha_p = (const float*)d_in[8];
  const float* eps_p   = (const float*)d_in[9];
  float* out = (float*)d_out;

  const int  N  = in_sizes[0] / 256;            // 100000
  const long MP = ((long)N + 255) & ~255L;      // padded rows (100096 = 391*256)
  const int  ntiles = (int)(MP / 256);          // 391
  const int  nwg    = 2 * ntiles;               // 782

  // ws layout: xh (bf16 x -> h2) | bufA (h0 -> h3) | bufB (xq fp8 -> h1) |
  //            Wt1 | Wt2 | h0q (fp8) | partials (2*ntiles*4 rows x 256) | stats
  unsigned short* xh   = (unsigned short*)d_ws;
  unsigned short* bufA = xh + MP * 256;
  unsigned short* bufB = bufA + MP * 256;
  unsigned short* Wt1  = bufB + MP * 256;
  unsigned short* Wt2  = Wt1 + 256 * 256;
  unsigned char*  h0q  = (unsigned char*)(Wt2 + 256 * 256);   // MP*256 bytes
  float* partials = (float*)(h0q + MP * 256);   // 2*ntiles*4*256 floats
  float* stats    = partials + (long)2 * ntiles * 4 * 256;
  unsigned char*  xq = (unsigned char*)bufB;    // aliases bufB (dead before h1)

  x2bf_kernel<<<(N * 32 + 255) / 256, 256, 0, stream>>>(x, xh, xq, N * 32);
  prep_kernel<<<256, 256, 0, stream>>>(W1, W2, Wt1, Wt2);
  aggregate_kernel<<<(N + 3) / 4, 256, 0, stream>>>(xq, nbr, bufA, h0q, N);
  combine_kernel<<<(N + 3) / 4, 256, 0, stream>>>(bufA, h0q, nbr, xh,
                                                  alpha_p, eps_p, bufB, N);

  gemm_w_kernel<0><<<nwg, 512, 0, stream>>>(bufB, Wt1, b1, xh, nullptr, N, nwg);
  gemm_w_kernel<1><<<nwg, 512, 0, stream>>>(xh, Wt2, b2, bufA, partials, N, nwg);

  bn_finalize_kernel<<<256, 256, 0, stream>>>(gamma, beta, partials, stats, N, ntiles);
  bn_norm_kernel<<<(N * 32 + 255) / 256, 256, 0, stream>>>(bufA, stats, out, N * 32);
}